// Round 8
// baseline (1157.284 us; speedup 1.0000x reference)
//
#include <hip/hip_runtime.h>
#include <hip/hip_bf16.h>
#include <math.h>

// SeaLiceGLKAN — fp32 in/out. Dense matvecs: lane=col, 8 nodes/wave, vector weight
// loads + scalar (wave-uniform) z loads. Edge gathers lane=H with bf16 payloads.
// z_t col-major [row][node]: rows 0..63 h, 64..68 env, 69..132 p.

constexpr int cB = 2, cT = 4, cN = 10000, cF = 16, cH = 64, cE = 160000, cNB = 8, cK = 3;
constexpr int cBN = cB * cN;    // 20000
constexpr int cBNH = cBN * cH;  // 1,280,000
constexpr int NBLK = (cBN + 63) / 64;  // 313 nodegroups of 64

typedef const float* fp;
typedef __hip_bfloat16 bh;

__device__ __forceinline__ float wmax(float v) {
#pragma unroll
  for (int o = 1; o < 64; o <<= 1) v = fmaxf(v, __shfl_xor(v, o, 64));
  return v;
}

// ---------------- CSR build ----------------
__global__ void k_zero_i32(int* p, int n) {
  int i = blockIdx.x * 256 + threadIdx.x;
  if (i < n) p[i] = 0;
}

__global__ void k_count(const int* dst, int* counts) {
  int e = blockIdx.x * 256 + threadIdx.x;
  if (e < cE) atomicAdd(&counts[dst[e]], 1);
}

__global__ void k_scan(const int* counts, int* row_ptr, int* cursor) {
  __shared__ int part[1024];
  int t = threadIdx.x;
  const int CH = (cN + 1023) / 1024;  // 10
  int s = 0;
  for (int i = 0; i < CH; i++) {
    int idx = t * CH + i;
    if (idx < cN) s += counts[idx];
  }
  part[t] = s;
  __syncthreads();
  for (int off = 1; off < 1024; off <<= 1) {
    int v = (t >= off) ? part[t - off] : 0;
    __syncthreads();
    part[t] += v;
    __syncthreads();
  }
  int excl = (t == 0) ? 0 : part[t - 1];
  for (int i = 0; i < CH; i++) {
    int idx = t * CH + i;
    if (idx < cN) {
      row_ptr[idx] = excl;
      cursor[idx] = excl;
      excl += counts[idx];
    }
  }
  if (t == 1023) row_ptr[cN] = part[1023];
}

__global__ void k_scatter(const int* src, const int* dst, fp ea, fp w1, fp b1, fp w2, fp b2,
                          int* cursor, int* esrc, float* gcsr) {
  int e = blockIdx.x * 256 + threadIdx.x;
  if (e >= cE) return;
  float a0 = ea[e * 4 + 0], a1 = ea[e * 4 + 1], a2 = ea[e * 4 + 2], a3 = ea[e * 4 + 3];
  float acc = b2[0];
#pragma unroll
  for (int j = 0; j < 16; j++) {
    float tv = b1[j] + a0 * w1[j] + a1 * w1[16 + j] + a2 * w1[32 + j] + a3 * w1[48 + j];
    acc += tanhf(tv) * w2[j];
  }
  float g = 1.f / (1.f + expf(-acc));
  int p = atomicAdd(&cursor[dst[e]], 1);
  esrc[p] = src[e];
  gcsr[p] = g;
}

__global__ void k_init(float* h, bh* h_bf, float* z_t, fp h0) {
  int i = blockIdx.x * 256 + threadIdx.x;
  if (i < cBNH) {
    float v = h0[i & 63];
    h[i] = v;
    h_bf[i] = __float2bfloat16(v);
    z_t[i] = h0[i / cBN];  // rows 0..63 col-major
  }
}

// ---------------- phi (RBF basis) col-major + env rows of z_t ----------------
__global__ __launch_bounds__(256) void k_phi(fp x, int t, fp c_enc, float* phi_t, float* z_t) {
  int lane = threadIdx.x & 63, q = threadIdx.x >> 6;
  int node = blockIdx.x * 64 + lane;
  if (node >= cBN) return;
  int b = node / cN, n = node - b * cN;
  const float* xp = x + (((size_t)b * cT + t) * cN + n) * cF;
  float ec0 = c_enc[0], ec7 = c_enc[7];
  float inv_e = 7.f / (ec7 - ec0);
  for (int f = q * 4; f < q * 4 + 4; f++) {
    float xv = xp[f];
#pragma unroll
    for (int cb = 0; cb < 8; cb++) {
      float d = (xv - c_enc[cb]) * inv_e;
      phi_t[(size_t)(f * 8 + cb) * cBN + node] = __expf(-d * d);
    }
  }
  if (q == 0) {
#pragma unroll
    for (int j = 0; j < 5; j++) z_t[(size_t)(64 + j) * cBN + node] = xp[8 + j];
  }
}

// ---------------- hop matvec: node-major input via LDS, lane=node ----------------
__global__ __launch_bounds__(256) void k_hop_mat_t(const float* vin_nm, fp Wh, fp avs, fp avd,
                                                   bh* hw_bf, float* ssrc, float* sdst) {
  __shared__ float tin[64 * 65];
  __shared__ float tout[64 * 65];
  __shared__ float red1[4][64], red2[4][64];
  int w = threadIdx.x >> 6, lane = threadIdx.x & 63;
  int base = blockIdx.x * 64, node = base + lane;
  int c0 = __builtin_amdgcn_readfirstlane(w * 16);
  {
    int tn = threadIdx.x >> 2, f0 = (threadIdx.x & 3) * 16;
    int gn = base + tn;
    if (gn >= cBN) gn = cBN - 1;
    const float4* vsrc = (const float4*)(vin_nm + (size_t)gn * 64 + f0);
#pragma unroll
    for (int q = 0; q < 4; q++) {
      float4 v = vsrc[q];
      int o = tn * 65 + f0 + q * 4;
      tin[o + 0] = v.x; tin[o + 1] = v.y; tin[o + 2] = v.z; tin[o + 3] = v.w;
    }
  }
  __syncthreads();
  float acc[16];
#pragma unroll
  for (int c = 0; c < 16; c++) acc[c] = 0.f;
  for (int i = 0; i < 64; i++) {
    float cv = tin[lane * 65 + i];
#pragma unroll
    for (int c = 0; c < 16; c++) acc[c] += cv * Wh[i * 64 + c0 + c];
  }
  float r1 = 0.f, r2 = 0.f;
#pragma unroll
  for (int c = 0; c < 16; c++) {
    r1 += acc[c] * avs[c0 + c];
    r2 += acc[c] * avd[c0 + c];
  }
  red1[w][lane] = r1;
  red2[w][lane] = r2;
#pragma unroll
  for (int c = 0; c < 16; c++) tout[(c0 + c) * 65 + lane] = acc[c];
  __syncthreads();
  if (w == 0 && node < cBN) {
    ssrc[node] = red1[0][lane] + red1[1][lane] + red1[2][lane] + red1[3][lane];
    sdst[node] = red2[0][lane] + red2[1][lane] + red2[2][lane] + red2[3][lane];
  }
  for (int r = w; r < 64; r += 4) {
    if (base + r < cBN)
      hw_bf[(size_t)(base + r) * 64 + lane] = __float2bfloat16(tout[lane * 65 + r]);
  }
}

// ---------------- hop aggregate (lane=H, bf16 gathers) + larval at hop 0 -------------
__global__ __launch_bounds__(256) void k_hop_agg(const bh* hw_bf, const float* ssrc,
                                                 const float* sdst, const int* row_ptr,
                                                 const int* esrc, const float* gcsr,
                                                 const bh* h_bf, float* cur_nm, float* khsum_nm,
                                                 float* agg_nm, int hop) {
  int w = threadIdx.x >> 6, lane = threadIdx.x & 63;
  int node = blockIdx.x * 4 + w;
  int b = node / cN, n = node - b * cN;
  int r0 = row_ptr[n], r1 = row_ptr[n + 1];
  const float* sb = ssrc + (size_t)b * cN;
  float sd = sdst[node];
  float m = -INFINITY;
  for (int e = r0 + lane; e < r1; e += 64) {
    float ev = sb[esrc[e]] + sd;
    ev = ev > 0.f ? ev : 0.2f * ev;
    m = fmaxf(m, ev);
  }
  m = wmax(m);
  float den = 0.f, num = 0.f, lacc = 0.f;
  const bh* hwb = hw_bf + (size_t)b * cN * cH;
  const bh* hb = h_bf + (size_t)b * cN * cH;
  for (int e = r0; e < r1; e++) {
    int s = esrc[e];
    float ev = sb[s] + sd;
    ev = ev > 0.f ? ev : 0.2f * ev;
    float wgt = expf(ev - m);
    den += wgt;
    num += wgt * __bfloat162float(hwb[(size_t)s * cH + lane]);
    if (hop == 0) lacc += gcsr[e] * __bfloat162float(hb[(size_t)s * cH + lane]);
  }
  float cv = num / (den + 1e-16f);
  size_t ni = (size_t)node * 64 + lane;
  if (hop < 2) cur_nm[ni] = cv;
  if (hop == 0) {
    khsum_nm[ni] = cv;
    agg_nm[ni] = lacc;
  } else {
    khsum_nm[ni] += cv;
  }
}

// ---------------- p finalize -> z_t rows 69..132 ----------------
__global__ __launch_bounds__(256) void k_pfin(float* z_t, const float* khsum_nm,
                                              const float* agg_nm, const int* row_ptr, fp W_lt) {
  __shared__ float tA[64 * 65];
  __shared__ float tK[64 * 65];
  int w = threadIdx.x >> 6, lane = threadIdx.x & 63;
  int base = blockIdx.x * 64, node = base + lane;
  int c0 = __builtin_amdgcn_readfirstlane(w * 16);
  {
    int tn = threadIdx.x >> 2, f0 = (threadIdx.x & 3) * 16;
    int gn = base + tn;
    if (gn >= cBN) gn = cBN - 1;
    const float4* asrc = (const float4*)(agg_nm + (size_t)gn * 64 + f0);
    const float4* ksrc = (const float4*)(khsum_nm + (size_t)gn * 64 + f0);
#pragma unroll
    for (int q = 0; q < 4; q++) {
      float4 a = asrc[q];
      float4 k = ksrc[q];
      int o = tn * 65 + f0 + q * 4;
      tA[o + 0] = a.x; tA[o + 1] = a.y; tA[o + 2] = a.z; tA[o + 3] = a.w;
      tK[o + 0] = k.x; tK[o + 1] = k.y; tK[o + 2] = k.z; tK[o + 3] = k.w;
    }
  }
  __syncthreads();
  int nd = node < cBN ? node : cBN - 1;
  int b = nd / cN, n = nd - b * cN;
  float pacc[16];
#pragma unroll
  for (int c = 0; c < 16; c++) pacc[c] = 0.f;
  for (int i = 0; i < 64; i++) {
    float av = tA[lane * 65 + i];
#pragma unroll
    for (int c = 0; c < 16; c++) pacc[c] += av * W_lt[i * 64 + c0 + c];
  }
  float idp = 1.f / ((float)(row_ptr[n + 1] - row_ptr[n]) + 1.f);
  if (node < cBN) {
#pragma unroll
    for (int c = 0; c < 16; c++) {
      z_t[(size_t)(69 + c0 + c) * cBN + node] =
          tK[lane * 65 + c0 + c] * (1.f / 3.f) + pacc[c] * idp;
    }
  }
}

// ---------------- dense matvecs: lane=col, 8 nodes/wave ----------------
// wave = (octet og, task): task 0 tau, 1 g, 2 u. Weights: coalesced vector loads.
// z/phi: wave-uniform scalar loads. Outputs node-major.
__global__ __launch_bounds__(256) void k_zmat_f(const float* z_t, const float* phi_t, fp W_tau,
                                                fp b_tau, fp W_g, fp b_g, fp W_enc, fp b_enc,
                                                float* tg_nm, float* u_nm) {
  int lane = threadIdx.x & 63;
  int wid = blockIdx.x * 4 + (threadIdx.x >> 6);
  int og = wid / 3, task = wid - og * 3;
  int nb = __builtin_amdgcn_readfirstlane(og * 8);
  float acc[8];
  if (task < 2) {
    const float* W = (task == 0) ? W_tau : W_g;
    float bv = ((task == 0) ? b_tau : b_g)[lane];
#pragma unroll
    for (int m = 0; m < 8; m++) acc[m] = bv;
    for (int k = 0; k < 133; k++) {
      const float* zr = z_t + (size_t)k * cBN + nb;
      float wv = W[k * 64 + lane];
#pragma unroll
      for (int m = 0; m < 8; m++) acc[m] += zr[m] * wv;
    }
#pragma unroll
    for (int m = 0; m < 8; m++) tg_nm[(size_t)(nb + m) * 128 + task * 64 + lane] = acc[m];
  } else {
    float bv = b_enc[lane];
#pragma unroll
    for (int m = 0; m < 8; m++) acc[m] = bv;
    for (int k = 0; k < 128; k++) {
      const float* pr = phi_t + (size_t)k * cBN + nb;
      float wv = W_enc[k * 64 + lane];
#pragma unroll
      for (int m = 0; m < 8; m++) acc[m] += pr[m] * wv;
    }
#pragma unroll
    for (int m = 0; m < 8; m++) u_nm[(size_t)(nb + m) * 64 + lane] = acc[m];
  }
}

// ---------------- light cell: liquid + LN + u + decoder + h stores ----------------
__global__ __launch_bounds__(256) void k_cell2(float* z_t, float* h, bh* h_bf,
                                               const float* tg_nm, const float* u_nm, fp gamma,
                                               fp beta, fp cdec, fp W_dec, fp b_dec, int t,
                                               float* out) {
  __shared__ float tT[128 * 65];  // rows 0..63 tau, 64..127 g; reused as h-transpose tile
  __shared__ float tU[64 * 65];
  __shared__ float redm[4][64], redv[4][64];
  __shared__ float redp[4][3][64];
  int w = threadIdx.x >> 6, lane = threadIdx.x & 63;
  int base = blockIdx.x * 64, node = base + lane;
  int nd = node < cBN ? node : cBN - 1;
  int bb = nd / cN, nn = nd - bb * cN;
  int c0 = __builtin_amdgcn_readfirstlane(w * 16);
  {
    int tn = threadIdx.x >> 2, fi = threadIdx.x & 3;
    int gn = base + tn;
    if (gn >= cBN) gn = cBN - 1;
    const float4* tsrc = (const float4*)(tg_nm + (size_t)gn * 128 + fi * 32);
#pragma unroll
    for (int q = 0; q < 8; q++) {
      float4 v = tsrc[q];
      int f = fi * 32 + q * 4;
      tT[(f + 0) * 65 + tn] = v.x; tT[(f + 1) * 65 + tn] = v.y;
      tT[(f + 2) * 65 + tn] = v.z; tT[(f + 3) * 65 + tn] = v.w;
    }
    const float4* usrc = (const float4*)(u_nm + (size_t)gn * 64 + fi * 16);
#pragma unroll
    for (int q = 0; q < 4; q++) {
      float4 v = usrc[q];
      int f = fi * 16 + q * 4;
      tU[(f + 0) * 65 + tn] = v.x; tU[(f + 1) * 65 + tn] = v.y;
      tU[(f + 2) * 65 + tn] = v.z; tU[(f + 3) * 65 + tn] = v.w;
    }
  }
  __syncthreads();
  float acc[16];
  float pm = 0.f;
#pragma unroll
  for (int c = 0; c < 16; c++) {
    float hcur = z_t[(size_t)(c0 + c) * cBN + nd];
    float at = tT[(c0 + c) * 65 + lane];
    float ag = tT[(64 + c0 + c) * 65 + lane];
    float tau = 1.f + 9.f / (1.f + __expf(-at));
    float g = tanhf(ag);
    float v = hcur + 0.25f * (g - hcur) / tau;
    acc[c] = v;
    pm += v;
  }
  redm[w][lane] = pm;
  __syncthreads();
  float mu = (redm[0][lane] + redm[1][lane] + redm[2][lane] + redm[3][lane]) * (1.f / 64.f);
  float pv = 0.f;
#pragma unroll
  for (int c = 0; c < 16; c++) {
    float d = acc[c] - mu;
    pv += d * d;
  }
  redv[w][lane] = pv;
  __syncthreads();
  float var = (redv[0][lane] + redv[1][lane] + redv[2][lane] + redv[3][lane]) * (1.f / 64.f);
  float rstd = rsqrtf(var + 1e-5f);
#pragma unroll
  for (int c = 0; c < 16; c++)
    acc[c] = (acc[c] - mu) * rstd * gamma[c0 + c] + beta[c0 + c] + tU[(c0 + c) * 65 + lane];
  // h stores: col-major z_t + stage transpose into tT (all tT reads completed pre-barriers)
  if (node < cBN) {
#pragma unroll
    for (int c = 0; c < 16; c++) z_t[(size_t)(c0 + c) * cBN + node] = acc[c];
  }
#pragma unroll
  for (int c = 0; c < 16; c++) tT[(c0 + c) * 65 + lane] = acc[c];
  float dc0 = cdec[0], dc7 = cdec[7];
  float inv_d = 7.f / (dc7 - dc0);
  float p0 = 0.f, p1 = 0.f, p2 = 0.f;
#pragma unroll
  for (int c = 0; c < 16; c++) {
#pragma unroll
    for (int j = 0; j < 8; j++) {
      float dd = (acc[c] - cdec[j]) * inv_d;
      float ph = __expf(-dd * dd);
      int bx = ((c0 + c) * 8 + j) * 3;
      p0 += ph * W_dec[bx];
      p1 += ph * W_dec[bx + 1];
      p2 += ph * W_dec[bx + 2];
    }
  }
  redp[w][0][lane] = p0;
  redp[w][1][lane] = p1;
  redp[w][2][lane] = p2;
  __syncthreads();
  for (int r = w; r < 64; r += 4) {
    if (base + r < cBN) {
      float v = tT[lane * 65 + r];
      h[(size_t)(base + r) * 64 + lane] = v;
      h_bf[(size_t)(base + r) * 64 + lane] = __float2bfloat16(v);
    }
  }
  if (w == 0 && node < cBN) {
    float v0 = redp[0][0][lane] + redp[1][0][lane] + redp[2][0][lane] + redp[3][0][lane] + b_dec[0];
    float v1 = redp[0][1][lane] + redp[1][1][lane] + redp[2][1][lane] + redp[3][1][lane] + b_dec[1];
    float v2 = redp[0][2][lane] + redp[1][2][lane] + redp[2][2][lane] + redp[3][2][lane] + b_dec[2];
    size_t ob = (((size_t)bb * cT + t) * cN + nn) * 3;
    out[ob] = fmaxf(v0, 0.f) + log1pf(expf(-fabsf(v0)));
    out[ob + 1] = fmaxf(v1, 0.f) + log1pf(expf(-fabsf(v1)));
    out[ob + 2] = fmaxf(v2, 0.f) + log1pf(expf(-fabsf(v2)));
  }
}

extern "C" void kernel_launch(void* const* d_in, const int* in_sizes, int n_in, void* d_out,
                              int out_size, void* d_ws, size_t ws_size, hipStream_t stream) {
  fp x = (fp)d_in[0];
  fp edge_attr = (fp)d_in[1];
  fp c_enc = (fp)d_in[2];
  fp W_enc = (fp)d_in[3];
  fp b_enc = (fp)d_in[4];
  fp W_hop = (fp)d_in[5];
  fp a_src = (fp)d_in[6];
  fp a_dst = (fp)d_in[7];
  fp w_lt1 = (fp)d_in[8];
  fp b_lt1 = (fp)d_in[9];
  fp w_lt2 = (fp)d_in[10];
  fp b_lt2 = (fp)d_in[11];
  fp W_lt = (fp)d_in[12];
  fp W_tau = (fp)d_in[13];
  fp b_tau = (fp)d_in[14];
  fp W_g = (fp)d_in[15];
  fp b_g = (fp)d_in[16];
  fp gamma = (fp)d_in[17];
  fp beta = (fp)d_in[18];
  fp c_dec = (fp)d_in[19];
  fp W_dec = (fp)d_in[20];
  fp b_dec = (fp)d_in[21];
  fp h0 = (fp)d_in[22];
  const int* eidx = (const int*)d_in[23];
  const int* esrc_in = eidx;
  const int* edst_in = eidx + cE;

  float* fws = (float*)d_ws;
  float* z_t = fws;      fws += 133 * cBN;  // col-major
  float* phi_t = fws;    fws += 128 * cBN;  // col-major
  float* h = fws;        fws += cBNH;       // node-major fp32
  float* khsum_nm = fws; fws += cBNH;       // node-major  } contiguous: aliased
  float* agg_nm = fws;   fws += cBNH;       // node-major  } as tg_nm (128/node)
  float* cur_nm = fws;   fws += cBNH;       // node-major; aliased as u_nm
  float* ssrc = fws;     fws += cBN;
  float* sdst = fws;     fws += cBN;
  float* gcsr = fws;     fws += cE;
  bh* h_bf = (bh*)fws;   fws += cBNH / 2;
  bh* hw_bf = (bh*)fws;  fws += cBNH / 2;
  int* iws = (int*)fws;
  int* esrc = iws;       iws += cE;
  int* row_ptr = iws;    iws += cN + 1;
  int* cursor = iws;     iws += cN;
  int* counts = iws;     iws += cN;
  float* tg_nm = khsum_nm;  // khsum/agg dead after pfin; tg live zmat->cell2
  float* u_nm = cur_nm;     // cur dead after last hop_mat; u live zmat->cell2

  k_zero_i32<<<(cN + 255) / 256, 256, 0, stream>>>(counts, cN);
  k_count<<<(cE + 255) / 256, 256, 0, stream>>>(edst_in, counts);
  k_scan<<<1, 1024, 0, stream>>>(counts, row_ptr, cursor);
  k_scatter<<<(cE + 255) / 256, 256, 0, stream>>>(esrc_in, edst_in, edge_attr, w_lt1, b_lt1,
                                                  w_lt2, b_lt2, cursor, esrc, gcsr);
  k_init<<<(cBNH + 255) / 256, 256, 0, stream>>>(h, h_bf, z_t, h0);

  for (int t = 0; t < cT; t++) {
    k_phi<<<NBLK, 256, 0, stream>>>(x, t, c_enc, phi_t, z_t);
    for (int k = 0; k < cK; k++) {
      k_hop_mat_t<<<NBLK, 256, 0, stream>>>(k == 0 ? h : cur_nm, W_hop + (size_t)k * cH * cH,
                                            a_src + k * cH, a_dst + k * cH, hw_bf, ssrc, sdst);
      k_hop_agg<<<cBN / 4, 256, 0, stream>>>(hw_bf, ssrc, sdst, row_ptr, esrc, gcsr, h_bf,
                                             cur_nm, khsum_nm, agg_nm, k);
    }
    k_pfin<<<NBLK, 256, 0, stream>>>(z_t, khsum_nm, agg_nm, row_ptr, W_lt);
    k_zmat_f<<<(2500 * 3) / 4, 256, 0, stream>>>(z_t, phi_t, W_tau, b_tau, W_g, b_g, W_enc,
                                                 b_enc, tg_nm, u_nm);
    k_cell2<<<NBLK, 256, 0, stream>>>(z_t, h, h_bf, tg_nm, u_nm, gamma, beta, c_dec, W_dec,
                                      b_dec, t, (float*)d_out);
  }
}

// Round 9
// 1001.597 us; speedup vs baseline: 1.1554x; 1.1554x over previous
//
#include <hip/hip_runtime.h>
#include <hip/hip_bf16.h>
#include <math.h>

// SeaLiceGLKAN — fp32 in/out. Dense matvecs: LDS-staged z tile, lane=node,
// wave-uniform scalar weights, col-major outputs. Edge gathers: two-phase
// softmax (lane=edge then lane=H with readlane broadcasts), bf16 payloads.
// z_t col-major [row][node]: rows 0..63 h, 64..68 env, 69..132 p.

constexpr int cB = 2, cT = 4, cN = 10000, cF = 16, cH = 64, cE = 160000, cNB = 8, cK = 3;
constexpr int cBN = cB * cN;    // 20000
constexpr int cBNH = cBN * cH;  // 1,280,000
constexpr int NBLK = (cBN + 63) / 64;  // 313 nodegroups of 64

typedef const float* fp;
typedef __hip_bfloat16 bh;

__device__ __forceinline__ float wmax(float v) {
#pragma unroll
  for (int o = 1; o < 64; o <<= 1) v = fmaxf(v, __shfl_xor(v, o, 64));
  return v;
}
__device__ __forceinline__ float wsum(float v) {
#pragma unroll
  for (int o = 1; o < 64; o <<= 1) v += __shfl_xor(v, o, 64);
  return v;
}

// ---------------- CSR build ----------------
__global__ void k_zero_i32(int* p, int n) {
  int i = blockIdx.x * 256 + threadIdx.x;
  if (i < n) p[i] = 0;
}

__global__ void k_count(const int* dst, int* counts) {
  int e = blockIdx.x * 256 + threadIdx.x;
  if (e < cE) atomicAdd(&counts[dst[e]], 1);
}

__global__ void k_scan(const int* counts, int* row_ptr, int* cursor) {
  __shared__ int part[1024];
  int t = threadIdx.x;
  const int CH = (cN + 1023) / 1024;  // 10
  int s = 0;
  for (int i = 0; i < CH; i++) {
    int idx = t * CH + i;
    if (idx < cN) s += counts[idx];
  }
  part[t] = s;
  __syncthreads();
  for (int off = 1; off < 1024; off <<= 1) {
    int v = (t >= off) ? part[t - off] : 0;
    __syncthreads();
    part[t] += v;
    __syncthreads();
  }
  int excl = (t == 0) ? 0 : part[t - 1];
  for (int i = 0; i < CH; i++) {
    int idx = t * CH + i;
    if (idx < cN) {
      row_ptr[idx] = excl;
      cursor[idx] = excl;
      excl += counts[idx];
    }
  }
  if (t == 1023) row_ptr[cN] = part[1023];
}

__global__ void k_scatter(const int* src, const int* dst, fp ea, fp w1, fp b1, fp w2, fp b2,
                          int* cursor, int* esrc, float* gcsr) {
  int e = blockIdx.x * 256 + threadIdx.x;
  if (e >= cE) return;
  float a0 = ea[e * 4 + 0], a1 = ea[e * 4 + 1], a2 = ea[e * 4 + 2], a3 = ea[e * 4 + 3];
  float acc = b2[0];
#pragma unroll
  for (int j = 0; j < 16; j++) {
    float tv = b1[j] + a0 * w1[j] + a1 * w1[16 + j] + a2 * w1[32 + j] + a3 * w1[48 + j];
    acc += tanhf(tv) * w2[j];
  }
  float g = 1.f / (1.f + expf(-acc));
  int p = atomicAdd(&cursor[dst[e]], 1);
  esrc[p] = src[e];
  gcsr[p] = g;
}

__global__ void k_init(float* h, bh* h_bf, float* z_t, fp h0) {
  int i = blockIdx.x * 256 + threadIdx.x;
  if (i < cBNH) {
    float v = h0[i & 63];
    h[i] = v;
    h_bf[i] = __float2bfloat16(v);
    z_t[i] = h0[i / cBN];  // rows 0..63 col-major
  }
}

// ---------------- hop matvec: node-major input via LDS, lane=node ----------------
__global__ __launch_bounds__(256) void k_hop_mat_t(const float* vin_nm, fp Wh, fp avs, fp avd,
                                                   bh* hw_bf, float* ssrc, float* sdst) {
  __shared__ float tin[64 * 65];
  __shared__ float tout[64 * 65];
  __shared__ float red1[4][64], red2[4][64];
  int w = threadIdx.x >> 6, lane = threadIdx.x & 63;
  int base = blockIdx.x * 64, node = base + lane;
  int c0 = __builtin_amdgcn_readfirstlane(w * 16);
  {
    int tn = threadIdx.x >> 2, f0 = (threadIdx.x & 3) * 16;
    int gn = base + tn;
    if (gn >= cBN) gn = cBN - 1;
    const float4* vsrc = (const float4*)(vin_nm + (size_t)gn * 64 + f0);
#pragma unroll
    for (int q = 0; q < 4; q++) {
      float4 v = vsrc[q];
      int o = tn * 65 + f0 + q * 4;
      tin[o + 0] = v.x; tin[o + 1] = v.y; tin[o + 2] = v.z; tin[o + 3] = v.w;
    }
  }
  __syncthreads();
  float acc[16];
#pragma unroll
  for (int c = 0; c < 16; c++) acc[c] = 0.f;
  for (int i = 0; i < 64; i++) {
    float cv = tin[lane * 65 + i];
#pragma unroll
    for (int c = 0; c < 16; c++) acc[c] += cv * Wh[i * 64 + c0 + c];
  }
  float r1 = 0.f, r2 = 0.f;
#pragma unroll
  for (int c = 0; c < 16; c++) {
    r1 += acc[c] * avs[c0 + c];
    r2 += acc[c] * avd[c0 + c];
  }
  red1[w][lane] = r1;
  red2[w][lane] = r2;
#pragma unroll
  for (int c = 0; c < 16; c++) tout[(c0 + c) * 65 + lane] = acc[c];
  __syncthreads();
  if (w == 0 && node < cBN) {
    ssrc[node] = red1[0][lane] + red1[1][lane] + red1[2][lane] + red1[3][lane];
    sdst[node] = red2[0][lane] + red2[1][lane] + red2[2][lane] + red2[3][lane];
  }
  for (int r = w; r < 64; r += 4) {
    if (base + r < cBN)
      hw_bf[(size_t)(base + r) * 64 + lane] = __float2bfloat16(tout[lane * 65 + r]);
  }
}

// ---------------- hop aggregate: two-phase softmax, readlane broadcasts -------------
__global__ __launch_bounds__(256) void k_hop_agg(const bh* hw_bf, const float* ssrc,
                                                 const float* sdst, const int* row_ptr,
                                                 const int* esrc, const float* gcsr,
                                                 const bh* h_bf, float* cur_nm, float* khsum_nm,
                                                 float* agg_nm, int hop) {
  int w = threadIdx.x >> 6, lane = threadIdx.x & 63;
  int node = blockIdx.x * 4 + w;
  int b = node / cN, n = node - b * cN;
  int r0 = row_ptr[n], r1 = row_ptr[n + 1];
  const float* sb = ssrc + (size_t)b * cN;
  float sd = sdst[node];
  // phase 1a: max (lane = edge)
  float m = -INFINITY;
  for (int e0 = r0; e0 < r1; e0 += 64) {
    int e = e0 + lane;
    if (e < r1) {
      float ev = sb[esrc[e]] + sd;
      ev = ev > 0.f ? ev : 0.2f * ev;
      m = fmaxf(m, ev);
    }
  }
  m = wmax(m);
  float den = 0.f, num = 0.f, lacc = 0.f;
  const bh* hwb = hw_bf + (size_t)b * cN * cH;
  const bh* hb = h_bf + (size_t)b * cN * cH;
  for (int e0 = r0; e0 < r1; e0 += 64) {
    int e = e0 + lane;
    bool vld = e < r1;
    // phase 1b: per-edge alpha (lane = edge, coalesced)
    int s = vld ? esrc[e] : 0;
    float g = (hop == 0 && vld) ? gcsr[e] : 0.f;
    float a = 0.f;
    if (vld) {
      float ev = sb[s] + sd;
      ev = ev > 0.f ? ev : 0.2f * ev;
      a = __expf(ev - m);
    }
    den += a;
    // phase 2: weighted gather (lane = H); s_j/a_j/g_j broadcast via readlane
    int cnt = min(64, r1 - e0);
    for (int j = 0; j < cnt; j++) {
      int sj = __builtin_amdgcn_readlane(s, j);
      float aj = __uint_as_float(__builtin_amdgcn_readlane(__float_as_uint(a), j));
      num += aj * __bfloat162float(hwb[(size_t)sj * cH + lane]);
      if (hop == 0) {
        float gj = __uint_as_float(__builtin_amdgcn_readlane(__float_as_uint(g), j));
        lacc += gj * __bfloat162float(hb[(size_t)sj * cH + lane]);
      }
    }
  }
  den = wsum(den);
  float cv = num / (den + 1e-16f);
  size_t ni = (size_t)node * 64 + lane;
  if (hop < 2) cur_nm[ni] = cv;
  if (hop == 0) {
    khsum_nm[ni] = cv;
    agg_nm[ni] = lacc;
  } else {
    khsum_nm[ni] += cv;
  }
}

// ---------------- p finalize -> z_t rows 69..132, env rows 64..68 ----------------
__global__ __launch_bounds__(256) void k_pfin(float* z_t, const float* khsum_nm,
                                              const float* agg_nm, const int* row_ptr, fp W_lt,
                                              fp x, int t) {
  __shared__ float tA[64 * 65];
  __shared__ float tK[64 * 65];
  int w = threadIdx.x >> 6, lane = threadIdx.x & 63;
  int base = blockIdx.x * 64, node = base + lane;
  int c0 = __builtin_amdgcn_readfirstlane(w * 16);
  {
    int tn = threadIdx.x >> 2, f0 = (threadIdx.x & 3) * 16;
    int gn = base + tn;
    if (gn >= cBN) gn = cBN - 1;
    const float4* asrc = (const float4*)(agg_nm + (size_t)gn * 64 + f0);
    const float4* ksrc = (const float4*)(khsum_nm + (size_t)gn * 64 + f0);
#pragma unroll
    for (int q = 0; q < 4; q++) {
      float4 a = asrc[q];
      float4 k = ksrc[q];
      int o = tn * 65 + f0 + q * 4;
      tA[o + 0] = a.x; tA[o + 1] = a.y; tA[o + 2] = a.z; tA[o + 3] = a.w;
      tK[o + 0] = k.x; tK[o + 1] = k.y; tK[o + 2] = k.z; tK[o + 3] = k.w;
    }
  }
  __syncthreads();
  int nd = node < cBN ? node : cBN - 1;
  int b = nd / cN, n = nd - b * cN;
  float pacc[16];
#pragma unroll
  for (int c = 0; c < 16; c++) pacc[c] = 0.f;
  for (int i = 0; i < 64; i++) {
    float av = tA[lane * 65 + i];
#pragma unroll
    for (int c = 0; c < 16; c++) pacc[c] += av * W_lt[i * 64 + c0 + c];
  }
  float idp = 1.f / ((float)(row_ptr[n + 1] - row_ptr[n]) + 1.f);
  if (node < cBN) {
#pragma unroll
    for (int c = 0; c < 16; c++) {
      z_t[(size_t)(69 + c0 + c) * cBN + node] =
          tK[lane * 65 + c0 + c] * (1.f / 3.f) + pacc[c] * idp;
    }
    if (w == 0) {
      const float* xp = x + (((size_t)b * cT + t) * cN + n) * cF;
#pragma unroll
      for (int j = 0; j < 5; j++) z_t[(size_t)(64 + j) * cBN + node] = xp[8 + j];
    }
  }
}

// ---------------- dense matvecs: LDS-staged z tile, col-split ----------------
// block = (nodegroup, task): tasks 0..3 -> 32 cols of [tau|g] over full K=133;
// tasks 4..5 -> 32 cols of encoder u with phi computed inline from x.
__global__ __launch_bounds__(256) void k_zmat2(const float* z_t, fp x, int t, fp W_tau, fp b_tau,
                                               fp W_g, fp b_g, fp c_enc, fp W_enc, fp b_enc,
                                               float* tg_cm, float* u_cm) {
  __shared__ float tz[133 * 65];  // z tile; u-task reuses first 64*17 as sx
  int w = threadIdx.x >> 6, lane = threadIdx.x & 63;
  int ng = blockIdx.x / 6, task = blockIdx.x - ng * 6;
  int base = ng * 64, node = base + lane;
  if (task < 4) {
    for (int i = threadIdx.x; i < 133 * 16; i += 256) {
      int row = i >> 4, q = i & 15;
      float4 v = *(const float4*)(z_t + (size_t)row * cBN + base + q * 4);
      int o = row * 65 + q * 4;
      tz[o + 0] = v.x; tz[o + 1] = v.y; tz[o + 2] = v.z; tz[o + 3] = v.w;
    }
    __syncthreads();
    bool isT = task < 2;
    const float* W = isT ? W_tau : W_g;
    const float* bias = isT ? b_tau : b_g;
    int cc = __builtin_amdgcn_readfirstlane((task & 1) * 32 + w * 8);
    float acc[8];
#pragma unroll
    for (int c = 0; c < 8; c++) acc[c] = bias[cc + c];
    for (int k = 0; k < 133; k++) {
      float zv = tz[k * 65 + lane];
#pragma unroll
      for (int c = 0; c < 8; c++) acc[c] += zv * W[k * 64 + cc + c];
    }
    if (node < cBN) {
      int rowbase = (isT ? 0 : 64) + cc;
#pragma unroll
      for (int c = 0; c < 8; c++) tg_cm[(size_t)(rowbase + c) * cBN + node] = acc[c];
    }
  } else {
    float* sx = tz;
    {
      int tn = threadIdx.x >> 2, f4 = (threadIdx.x & 3) * 4;
      int gn = base + tn;
      if (gn >= cBN) gn = cBN - 1;
      int gb = gn / cN, gnn = gn - gb * cN;
      float4 xv = *(const float4*)(x + (((size_t)gb * cT + t) * cN + gnn) * cF + f4);
      sx[tn * 17 + f4 + 0] = xv.x;
      sx[tn * 17 + f4 + 1] = xv.y;
      sx[tn * 17 + f4 + 2] = xv.z;
      sx[tn * 17 + f4 + 3] = xv.w;
    }
    __syncthreads();
    int cu = __builtin_amdgcn_readfirstlane((task - 4) * 32 + w * 8);
    float ce[8];
#pragma unroll
    for (int cb = 0; cb < 8; cb++) ce[cb] = c_enc[cb];
    float inv_e = 7.f / (ce[7] - ce[0]);
    float acc[8];
#pragma unroll
    for (int c = 0; c < 8; c++) acc[c] = b_enc[cu + c];
    for (int f = 0; f < 16; f++) {
      float xv = sx[lane * 17 + f];
#pragma unroll
      for (int cb = 0; cb < 8; cb++) {
        float d = (xv - ce[cb]) * inv_e;
        float ph = __expf(-d * d);
        const float* Wr = W_enc + (f * 8 + cb) * 64 + cu;
#pragma unroll
        for (int c = 0; c < 8; c++) acc[c] += ph * Wr[c];
      }
    }
    if (node < cBN) {
#pragma unroll
      for (int c = 0; c < 8; c++) u_cm[(size_t)(cu + c) * cBN + node] = acc[c];
    }
  }
}

// ---------------- light cell: liquid + LN + u + decoder + h stores ----------------
__global__ __launch_bounds__(256) void k_cell2(float* z_t, float* h, bh* h_bf,
                                               const float* tg_cm, const float* u_cm, fp gamma,
                                               fp beta, fp cdec, fp W_dec, fp b_dec, int t,
                                               float* out) {
  __shared__ float tT[128 * 65];  // rows 0..63 tau, 64..127 g; reused as transpose tile
  __shared__ float tU[64 * 65];
  __shared__ float redm[4][64], redv[4][64];
  __shared__ float redp[4][3][64];
  int w = threadIdx.x >> 6, lane = threadIdx.x & 63;
  int base = blockIdx.x * 64, node = base + lane;
  int nd = node < cBN ? node : cBN - 1;
  int bb = nd / cN, nn = nd - bb * cN;
  int c0 = __builtin_amdgcn_readfirstlane(w * 16);
  for (int i = threadIdx.x; i < 128 * 16; i += 256) {
    int row = i >> 4, q = i & 15;
    float4 v = *(const float4*)(tg_cm + (size_t)row * cBN + base + q * 4);
    int o = row * 65 + q * 4;
    tT[o + 0] = v.x; tT[o + 1] = v.y; tT[o + 2] = v.z; tT[o + 3] = v.w;
  }
  for (int i = threadIdx.x; i < 64 * 16; i += 256) {
    int row = i >> 4, q = i & 15;
    float4 v = *(const float4*)(u_cm + (size_t)row * cBN + base + q * 4);
    int o = row * 65 + q * 4;
    tU[o + 0] = v.x; tU[o + 1] = v.y; tU[o + 2] = v.z; tU[o + 3] = v.w;
  }
  __syncthreads();
  float acc[16];
  float pm = 0.f;
#pragma unroll
  for (int c = 0; c < 16; c++) {
    float hcur = z_t[(size_t)(c0 + c) * cBN + nd];
    float at = tT[(c0 + c) * 65 + lane];
    float ag = tT[(64 + c0 + c) * 65 + lane];
    float tau = 1.f + 9.f / (1.f + __expf(-at));
    float g = tanhf(ag);
    float v = hcur + 0.25f * (g - hcur) / tau;
    acc[c] = v;
    pm += v;
  }
  redm[w][lane] = pm;
  __syncthreads();
  float mu = (redm[0][lane] + redm[1][lane] + redm[2][lane] + redm[3][lane]) * (1.f / 64.f);
  float pv = 0.f;
#pragma unroll
  for (int c = 0; c < 16; c++) {
    float d = acc[c] - mu;
    pv += d * d;
  }
  redv[w][lane] = pv;
  __syncthreads();
  float var = (redv[0][lane] + redv[1][lane] + redv[2][lane] + redv[3][lane]) * (1.f / 64.f);
  float rstd = rsqrtf(var + 1e-5f);
#pragma unroll
  for (int c = 0; c < 16; c++)
    acc[c] = (acc[c] - mu) * rstd * gamma[c0 + c] + beta[c0 + c] + tU[(c0 + c) * 65 + lane];
  if (node < cBN) {
#pragma unroll
    for (int c = 0; c < 16; c++) z_t[(size_t)(c0 + c) * cBN + node] = acc[c];
  }
  __syncthreads();  // tT reads done by all waves before overwrite
#pragma unroll
  for (int c = 0; c < 16; c++) tT[(c0 + c) * 65 + lane] = acc[c];
  float dc0 = cdec[0], dc7 = cdec[7];
  float inv_d = 7.f / (dc7 - dc0);
  float p0 = 0.f, p1 = 0.f, p2 = 0.f;
#pragma unroll
  for (int c = 0; c < 16; c++) {
#pragma unroll
    for (int j = 0; j < 8; j++) {
      float dd = (acc[c] - cdec[j]) * inv_d;
      float ph = __expf(-dd * dd);
      int bx = ((c0 + c) * 8 + j) * 3;
      p0 += ph * W_dec[bx];
      p1 += ph * W_dec[bx + 1];
      p2 += ph * W_dec[bx + 2];
    }
  }
  redp[w][0][lane] = p0;
  redp[w][1][lane] = p1;
  redp[w][2][lane] = p2;
  __syncthreads();
  for (int r = w; r < 64; r += 4) {
    if (base + r < cBN) {
      float v = tT[lane * 65 + r];
      h[(size_t)(base + r) * 64 + lane] = v;
      h_bf[(size_t)(base + r) * 64 + lane] = __float2bfloat16(v);
    }
  }
  if (w == 0 && node < cBN) {
    float v0 = redp[0][0][lane] + redp[1][0][lane] + redp[2][0][lane] + redp[3][0][lane] + b_dec[0];
    float v1 = redp[0][1][lane] + redp[1][1][lane] + redp[2][1][lane] + redp[3][1][lane] + b_dec[1];
    float v2 = redp[0][2][lane] + redp[1][2][lane] + redp[2][2][lane] + redp[3][2][lane] + b_dec[2];
    size_t ob = (((size_t)bb * cT + t) * cN + nn) * 3;
    out[ob] = fmaxf(v0, 0.f) + log1pf(expf(-fabsf(v0)));
    out[ob + 1] = fmaxf(v1, 0.f) + log1pf(expf(-fabsf(v1)));
    out[ob + 2] = fmaxf(v2, 0.f) + log1pf(expf(-fabsf(v2)));
  }
}

extern "C" void kernel_launch(void* const* d_in, const int* in_sizes, int n_in, void* d_out,
                              int out_size, void* d_ws, size_t ws_size, hipStream_t stream) {
  fp x = (fp)d_in[0];
  fp edge_attr = (fp)d_in[1];
  fp c_enc = (fp)d_in[2];
  fp W_enc = (fp)d_in[3];
  fp b_enc = (fp)d_in[4];
  fp W_hop = (fp)d_in[5];
  fp a_src = (fp)d_in[6];
  fp a_dst = (fp)d_in[7];
  fp w_lt1 = (fp)d_in[8];
  fp b_lt1 = (fp)d_in[9];
  fp w_lt2 = (fp)d_in[10];
  fp b_lt2 = (fp)d_in[11];
  fp W_lt = (fp)d_in[12];
  fp W_tau = (fp)d_in[13];
  fp b_tau = (fp)d_in[14];
  fp W_g = (fp)d_in[15];
  fp b_g = (fp)d_in[16];
  fp gamma = (fp)d_in[17];
  fp beta = (fp)d_in[18];
  fp c_dec = (fp)d_in[19];
  fp W_dec = (fp)d_in[20];
  fp b_dec = (fp)d_in[21];
  fp h0 = (fp)d_in[22];
  const int* eidx = (const int*)d_in[23];
  const int* esrc_in = eidx;
  const int* edst_in = eidx + cE;

  float* fws = (float*)d_ws;
  float* z_t = fws;      fws += 133 * cBN;  // col-major
  float* khsum_nm = fws; fws += cBNH;       // node-major } contiguous 128 rows:
  float* agg_nm = fws;   fws += cBNH;       // node-major } aliased as tg_cm
  float* cur_nm = fws;   fws += cBNH;       // node-major; aliased as u_cm
  float* h = fws;        fws += cBNH;       // node-major fp32
  float* ssrc = fws;     fws += cBN;
  float* sdst = fws;     fws += cBN;
  float* gcsr = fws;     fws += cE;
  bh* h_bf = (bh*)fws;   fws += cBNH / 2;
  bh* hw_bf = (bh*)fws;  fws += cBNH / 2;
  int* iws = (int*)fws;
  int* esrc = iws;       iws += cE;
  int* row_ptr = iws;    iws += cN + 1;
  int* cursor = iws;     iws += cN;
  int* counts = iws;     iws += cN;
  float* tg_cm = khsum_nm;  // [128][cBN]; khsum/agg dead after pfin
  float* u_cm = cur_nm;     // [64][cBN]; cur dead after last hop_mat

  k_zero_i32<<<(cN + 255) / 256, 256, 0, stream>>>(counts, cN);
  k_count<<<(cE + 255) / 256, 256, 0, stream>>>(edst_in, counts);
  k_scan<<<1, 1024, 0, stream>>>(counts, row_ptr, cursor);
  k_scatter<<<(cE + 255) / 256, 256, 0, stream>>>(esrc_in, edst_in, edge_attr, w_lt1, b_lt1,
                                                  w_lt2, b_lt2, cursor, esrc, gcsr);
  k_init<<<(cBNH + 255) / 256, 256, 0, stream>>>(h, h_bf, z_t, h0);

  for (int t = 0; t < cT; t++) {
    for (int k = 0; k < cK; k++) {
      k_hop_mat_t<<<NBLK, 256, 0, stream>>>(k == 0 ? h : cur_nm, W_hop + (size_t)k * cH * cH,
                                            a_src + k * cH, a_dst + k * cH, hw_bf, ssrc, sdst);
      k_hop_agg<<<cBN / 4, 256, 0, stream>>>(hw_bf, ssrc, sdst, row_ptr, esrc, gcsr, h_bf,
                                             cur_nm, khsum_nm, agg_nm, k);
    }
    k_pfin<<<NBLK, 256, 0, stream>>>(z_t, khsum_nm, agg_nm, row_ptr, W_lt, x, t);
    k_zmat2<<<NBLK * 6, 256, 0, stream>>>(z_t, x, t, W_tau, b_tau, W_g, b_g, c_enc, W_enc,
                                          b_enc, tg_cm, u_cm);
    k_cell2<<<NBLK, 256, 0, stream>>>(z_t, h, h_bf, tg_cm, u_cm, gamma, beta, c_dec, W_dec,
                                      b_dec, t, (float*)d_out);
  }
}

// Round 10
// 740.706 us; speedup vs baseline: 1.5624x; 1.3522x over previous
//
#include <hip/hip_runtime.h>
#include <hip/hip_bf16.h>
#include <math.h>

// SeaLiceGLKAN — fp32 in/out. Dense per-step chain = ONE MFMA mega-kernel
// (bf16 GEMMs: agg@W_lt -> p, z@[Wtau|Wg], phi@W_enc; fp32 accum; fp32 h state).
// Edge gathers: two-phase softmax (lane=edge then lane=H readlane broadcasts), bf16.

constexpr int cB = 2, cT = 4, cN = 10000, cF = 16, cH = 64, cE = 160000, cNB = 8, cK = 3;
constexpr int cBN = cB * cN;    // 20000
constexpr int cBNH = cBN * cH;  // 1,280,000
constexpr int NBLK = (cBN + 63) / 64;  // 313 nodegroups of 64

typedef const float* fp;
typedef __hip_bfloat16 bh;
typedef short short8 __attribute__((ext_vector_type(8)));
typedef float f32x4 __attribute__((ext_vector_type(4)));

__device__ __forceinline__ float wmax(float v) {
#pragma unroll
  for (int o = 1; o < 64; o <<= 1) v = fmaxf(v, __shfl_xor(v, o, 64));
  return v;
}
__device__ __forceinline__ float wsum(float v) {
#pragma unroll
  for (int o = 1; o < 64; o <<= 1) v += __shfl_xor(v, o, 64);
  return v;
}
__device__ __forceinline__ unsigned short f2b(float f) {  // fp32 -> bf16 bits (RNE)
  unsigned u = __float_as_uint(f);
  u += 0x7FFFu + ((u >> 16) & 1u);
  return (unsigned short)(u >> 16);
}

// ---------------- CSR build ----------------
__global__ void k_zero_i32(int* p, int n) {
  int i = blockIdx.x * 256 + threadIdx.x;
  if (i < n) p[i] = 0;
}

__global__ void k_count(const int* dst, int* counts) {
  int e = blockIdx.x * 256 + threadIdx.x;
  if (e < cE) atomicAdd(&counts[dst[e]], 1);
}

__global__ void k_scan(const int* counts, int* row_ptr, int* cursor) {
  __shared__ int part[1024];
  int t = threadIdx.x;
  const int CH = (cN + 1023) / 1024;  // 10
  int s = 0;
  for (int i = 0; i < CH; i++) {
    int idx = t * CH + i;
    if (idx < cN) s += counts[idx];
  }
  part[t] = s;
  __syncthreads();
  for (int off = 1; off < 1024; off <<= 1) {
    int v = (t >= off) ? part[t - off] : 0;
    __syncthreads();
    part[t] += v;
    __syncthreads();
  }
  int excl = (t == 0) ? 0 : part[t - 1];
  for (int i = 0; i < CH; i++) {
    int idx = t * CH + i;
    if (idx < cN) {
      row_ptr[idx] = excl;
      cursor[idx] = excl;
      excl += counts[idx];
    }
  }
  if (t == 1023) row_ptr[cN] = part[1023];
}

__global__ void k_scatter(const int* src, const int* dst, fp ea, fp w1, fp b1, fp w2, fp b2,
                          int* cursor, int* esrc, float* gcsr) {
  int e = blockIdx.x * 256 + threadIdx.x;
  if (e >= cE) return;
  float a0 = ea[e * 4 + 0], a1 = ea[e * 4 + 1], a2 = ea[e * 4 + 2], a3 = ea[e * 4 + 3];
  float acc = b2[0];
#pragma unroll
  for (int j = 0; j < 16; j++) {
    float tv = b1[j] + a0 * w1[j] + a1 * w1[16 + j] + a2 * w1[32 + j] + a3 * w1[48 + j];
    acc += tanhf(tv) * w2[j];
  }
  float g = 1.f / (1.f + expf(-acc));
  int p = atomicAdd(&cursor[dst[e]], 1);
  esrc[p] = src[e];
  gcsr[p] = g;
}

__global__ void k_init(float* h, bh* h_bf, fp h0) {
  int i = blockIdx.x * 256 + threadIdx.x;
  if (i < cBNH) {
    float v = h0[i & 63];
    h[i] = v;
    h_bf[i] = __float2bfloat16(v);
  }
}

// ---------------- weight prepack (col-major bf16, K padded) ----------------
__global__ void k_wpack(fp W_tau, fp W_g, fp W_enc, fp W_lt, unsigned short* Wtg,
                        unsigned short* Wenc, unsigned short* Wlt) {
  int i = blockIdx.x * 256 + threadIdx.x;
  if (i < 128 * 160) {
    int col = i / 160, k = i - col * 160;
    float v = 0.f;
    if (k < 133) v = (col < 64) ? W_tau[k * 64 + col] : W_g[k * 64 + (col - 64)];
    Wtg[i] = f2b(v);
  } else if (i < 128 * 160 + 64 * 128) {
    int i2 = i - 128 * 160;
    int col = i2 / 128, k = i2 - col * 128;
    Wenc[i2] = f2b(W_enc[k * 64 + col]);
  } else if (i < 128 * 160 + 64 * 128 + 64 * 64) {
    int i3 = i - 128 * 160 - 64 * 128;
    int col = i3 / 64, k = i3 - col * 64;
    Wlt[i3] = f2b(W_lt[k * 64 + col]);
  }
}

// ---------------- hop matvec: node-major input via LDS, lane=node ----------------
__global__ __launch_bounds__(256) void k_hop_mat_t(const float* vin_nm, fp Wh, fp avs, fp avd,
                                                   bh* hw_bf, float* ssrc, float* sdst) {
  __shared__ float tin[64 * 65];
  __shared__ float tout[64 * 65];
  __shared__ float red1[4][64], red2[4][64];
  int w = threadIdx.x >> 6, lane = threadIdx.x & 63;
  int base = blockIdx.x * 64, node = base + lane;
  int c0 = __builtin_amdgcn_readfirstlane(w * 16);
  {
    int tn = threadIdx.x >> 2, f0 = (threadIdx.x & 3) * 16;
    int gn = base + tn;
    if (gn >= cBN) gn = cBN - 1;
    const float4* vsrc = (const float4*)(vin_nm + (size_t)gn * 64 + f0);
#pragma unroll
    for (int q = 0; q < 4; q++) {
      float4 v = vsrc[q];
      int o = tn * 65 + f0 + q * 4;
      tin[o + 0] = v.x; tin[o + 1] = v.y; tin[o + 2] = v.z; tin[o + 3] = v.w;
    }
  }
  __syncthreads();
  float acc[16];
#pragma unroll
  for (int c = 0; c < 16; c++) acc[c] = 0.f;
  for (int i = 0; i < 64; i++) {
    float cv = tin[lane * 65 + i];
#pragma unroll
    for (int c = 0; c < 16; c++) acc[c] += cv * Wh[i * 64 + c0 + c];
  }
  float r1 = 0.f, r2 = 0.f;
#pragma unroll
  for (int c = 0; c < 16; c++) {
    r1 += acc[c] * avs[c0 + c];
    r2 += acc[c] * avd[c0 + c];
  }
  red1[w][lane] = r1;
  red2[w][lane] = r2;
#pragma unroll
  for (int c = 0; c < 16; c++) tout[(c0 + c) * 65 + lane] = acc[c];
  __syncthreads();
  if (w == 0 && node < cBN) {
    ssrc[node] = red1[0][lane] + red1[1][lane] + red1[2][lane] + red1[3][lane];
    sdst[node] = red2[0][lane] + red2[1][lane] + red2[2][lane] + red2[3][lane];
  }
  for (int r = w; r < 64; r += 4) {
    if (base + r < cBN)
      hw_bf[(size_t)(base + r) * 64 + lane] = __float2bfloat16(tout[lane * 65 + r]);
  }
}

// ---------------- hop aggregate: two-phase softmax, readlane broadcasts -------------
__global__ __launch_bounds__(256) void k_hop_agg(const bh* hw_bf, const float* ssrc,
                                                 const float* sdst, const int* row_ptr,
                                                 const int* esrc, const float* gcsr,
                                                 const bh* h_bf, float* cur_nm, float* khsum_nm,
                                                 float* agg_nm, int hop) {
  int w = threadIdx.x >> 6, lane = threadIdx.x & 63;
  int node = blockIdx.x * 4 + w;
  int b = node / cN, n = node - b * cN;
  int r0 = row_ptr[n], r1 = row_ptr[n + 1];
  const float* sb = ssrc + (size_t)b * cN;
  float sd = sdst[node];
  float m = -INFINITY;
  for (int e0 = r0; e0 < r1; e0 += 64) {
    int e = e0 + lane;
    if (e < r1) {
      float ev = sb[esrc[e]] + sd;
      ev = ev > 0.f ? ev : 0.2f * ev;
      m = fmaxf(m, ev);
    }
  }
  m = wmax(m);
  float den = 0.f, num = 0.f, lacc = 0.f;
  const bh* hwb = hw_bf + (size_t)b * cN * cH;
  const bh* hb = h_bf + (size_t)b * cN * cH;
  for (int e0 = r0; e0 < r1; e0 += 64) {
    int e = e0 + lane;
    bool vld = e < r1;
    int s = vld ? esrc[e] : 0;
    float g = (hop == 0 && vld) ? gcsr[e] : 0.f;
    float a = 0.f;
    if (vld) {
      float ev = sb[s] + sd;
      ev = ev > 0.f ? ev : 0.2f * ev;
      a = __expf(ev - m);
    }
    den += a;
    int cnt = min(64, r1 - e0);
    for (int j = 0; j < cnt; j++) {
      int sj = __builtin_amdgcn_readlane(s, j);
      float aj = __uint_as_float(__builtin_amdgcn_readlane(__float_as_uint(a), j));
      num += aj * __bfloat162float(hwb[(size_t)sj * cH + lane]);
      if (hop == 0) {
        float gj = __uint_as_float(__builtin_amdgcn_readlane(__float_as_uint(g), j));
        lacc += gj * __bfloat162float(hb[(size_t)sj * cH + lane]);
      }
    }
  }
  den = wsum(den);
  float cv = num / (den + 1e-16f);
  size_t ni = (size_t)node * 64 + lane;
  if (hop < 2) cur_nm[ni] = cv;
  if (hop == 0) {
    khsum_nm[ni] = cv;
    agg_nm[ni] = lacc;
  } else {
    khsum_nm[ni] += cv;
  }
}

// ---------------- MFMA mega-kernel: p-GEMM + tau/g GEMM + u GEMM + cell ----------------
// LDS map (overlaid, lifetimes disjoint):
//   [0, 21504)  tz   bf16 [64 node][168]: k 0..63 h, 64..68 env, 69..132 p, 133..159 zero
//   [21504, 30720) tagg bf16 [64][72]
//   [30720, 48128) tphi bf16 [64][136]
//   [0, 50432)  tgu  fp32 [64][197] (after tz/tagg/tphi dead): cols 0..63 tau, 64..127 g, 128..191 u
//   [50432, 54784) sx fp32 [64][17]
//   [54784, 59904) redm/redv/redp
__global__ __launch_bounds__(256) void k_mega(fp x, int t, float* h_nm, bh* h_bf,
                                              const float* khsum_nm, const float* agg_nm,
                                              const int* row_ptr, const unsigned short* Wtg,
                                              const unsigned short* Wenc,
                                              const unsigned short* Wlt, fp b_tau, fp b_g,
                                              fp b_enc, fp gamma, fp beta, fp c_enc, fp cdec,
                                              fp W_dec, fp b_dec, float* out) {
  __shared__ __align__(16) char lds[59904];
  unsigned short* tz = (unsigned short*)lds;
  unsigned short* tagg = (unsigned short*)(lds + 21504);
  unsigned short* tphi = (unsigned short*)(lds + 30720);
  float* tgu = (float*)lds;
  float* sx = (float*)(lds + 50432);
  float* redm = (float*)(lds + 54784);          // [4][64]
  float* redv = redm + 256;                     // [4][64]
  float* redp = redv + 256;                     // [4][3][64]
  int tid = threadIdx.x;
  int w = tid >> 6, lane = tid & 63;
  int quad = lane >> 4, l15 = lane & 15;
  int base = blockIdx.x * 64;
  // ---- stage: sx, tz h rows, tagg, zero pad rows ----
  {
    int tn = tid >> 2, f4 = (tid & 3) * 4;
    int gn = base + tn;
    if (gn >= cBN) gn = cBN - 1;
    int gb = gn / cN, gnn = gn - gb * cN;
    float4 xv = *(const float4*)(x + (((size_t)gb * cT + t) * cN + gnn) * cF + f4);
    sx[tn * 17 + f4 + 0] = xv.x;
    sx[tn * 17 + f4 + 1] = xv.y;
    sx[tn * 17 + f4 + 2] = xv.z;
    sx[tn * 17 + f4 + 3] = xv.w;
    int f0 = (tid & 3) * 16;
    const float4* hsrc = (const float4*)(h_nm + (size_t)gn * 64 + f0);
    const float4* asrc = (const float4*)(agg_nm + (size_t)gn * 64 + f0);
#pragma unroll
    for (int q = 0; q < 4; q++) {
      float4 hv = hsrc[q];
      float4 av = asrc[q];
      int k = f0 + q * 4;
      tz[tn * 168 + k + 0] = f2b(hv.x); tz[tn * 168 + k + 1] = f2b(hv.y);
      tz[tn * 168 + k + 2] = f2b(hv.z); tz[tn * 168 + k + 3] = f2b(hv.w);
      tagg[tn * 72 + k + 0] = f2b(av.x); tagg[tn * 72 + k + 1] = f2b(av.y);
      tagg[tn * 72 + k + 2] = f2b(av.z); tagg[tn * 72 + k + 3] = f2b(av.w);
    }
  }
  for (int i = tid; i < 64 * 27; i += 256) {
    int nn2 = i / 27, kk = 133 + (i - nn2 * 27);
    tz[nn2 * 168 + kk] = 0;
  }
  __syncthreads();
  // ---- env rows + phi (reads sx) ----
  for (int i = tid; i < 320; i += 256) {
    int j = i >> 6, n2 = i & 63;
    tz[n2 * 168 + 64 + j] = f2b(sx[n2 * 17 + 8 + j]);
  }
  {
    float ec0 = c_enc[0], ec7 = c_enc[7];
    float inv_e = 7.f / (ec7 - ec0);
    for (int i = tid; i < 64 * 128; i += 256) {
      int n2 = i >> 7, j = i & 127;
      int f = j >> 3, cb = j & 7;
      float d = (sx[n2 * 17 + f] - c_enc[cb]) * inv_e;
      tphi[n2 * 136 + j] = f2b(__expf(-d * d));
    }
  }
  __syncthreads();
  // ---- G2: u = phi @ Wenc (frags held in registers) ----
  f32x4 accU[4];
#pragma unroll
  for (int mt = 0; mt < 4; mt++) accU[mt] = (f32x4){0.f, 0.f, 0.f, 0.f};
#pragma unroll
  for (int ks = 0; ks < 4; ks++) {
    short8 bfr = *(const short8*)(Wenc + (16 * w + l15) * 128 + ks * 32 + quad * 8);
#pragma unroll
    for (int mt = 0; mt < 4; mt++) {
      short8 afr = *(const short8*)(tphi + (mt * 16 + l15) * 136 + ks * 32 + quad * 8);
      accU[mt] = __builtin_amdgcn_mfma_f32_16x16x32_bf16(afr, bfr, accU[mt], 0, 0, 0);
    }
  }
  // ---- G0: plt = agg @ Wlt -> p rows into tz ----
  {
    f32x4 accP[4];
#pragma unroll
    for (int mt = 0; mt < 4; mt++) accP[mt] = (f32x4){0.f, 0.f, 0.f, 0.f};
#pragma unroll
    for (int ks = 0; ks < 2; ks++) {
      short8 bfr = *(const short8*)(Wlt + (16 * w + l15) * 64 + ks * 32 + quad * 8);
#pragma unroll
      for (int mt = 0; mt < 4; mt++) {
        short8 afr = *(const short8*)(tagg + (mt * 16 + l15) * 72 + ks * 32 + quad * 8);
        accP[mt] = __builtin_amdgcn_mfma_f32_16x16x32_bf16(afr, bfr, accP[mt], 0, 0, 0);
      }
    }
    int colP = 16 * w + l15;
#pragma unroll
    for (int mt = 0; mt < 4; mt++) {
#pragma unroll
      for (int r = 0; r < 4; r++) {
        int nl = mt * 16 + quad * 4 + r;
        int ng = base + nl;
        int ngc = ng < cBN ? ng : cBN - 1;
        int bB = ngc / cN, nn = ngc - bB * cN;
        float deg = (float)(row_ptr[nn + 1] - row_ptr[nn]);
        float pval = khsum_nm[(size_t)ngc * 64 + colP] * (1.f / 3.f) +
                     accP[mt][r] / (deg + 1.f);
        tz[nl * 168 + 69 + colP] = f2b(pval);
      }
    }
  }
  __syncthreads();
  // ---- G1: [tau|g] = z @ Wtg (K=160) ----
  f32x4 accT[8];
#pragma unroll
  for (int i = 0; i < 8; i++) accT[i] = (f32x4){0.f, 0.f, 0.f, 0.f};
#pragma unroll
  for (int ks = 0; ks < 5; ks++) {
    short8 b0 = *(const short8*)(Wtg + (32 * w + l15) * 160 + ks * 32 + quad * 8);
    short8 b1 = *(const short8*)(Wtg + (32 * w + 16 + l15) * 160 + ks * 32 + quad * 8);
#pragma unroll
    for (int mt = 0; mt < 4; mt++) {
      short8 afr = *(const short8*)(tz + (mt * 16 + l15) * 168 + ks * 32 + quad * 8);
      accT[mt * 2 + 0] = __builtin_amdgcn_mfma_f32_16x16x32_bf16(afr, b0, accT[mt * 2 + 0], 0, 0, 0);
      accT[mt * 2 + 1] = __builtin_amdgcn_mfma_f32_16x16x32_bf16(afr, b1, accT[mt * 2 + 1], 0, 0, 0);
    }
  }
  __syncthreads();  // tz/tagg/tphi dead; tgu overlay begins
  // ---- write tau/g/u into tgu fp32 [node][197] ----
#pragma unroll
  for (int mt = 0; mt < 4; mt++) {
#pragma unroll
    for (int ntl = 0; ntl < 2; ntl++) {
#pragma unroll
      for (int r = 0; r < 4; r++) {
        int nl = mt * 16 + quad * 4 + r;
        int col = 32 * w + ntl * 16 + l15;
        tgu[nl * 197 + col] = accT[mt * 2 + ntl][r];
      }
    }
#pragma unroll
    for (int r = 0; r < 4; r++) {
      int nl = mt * 16 + quad * 4 + r;
      tgu[nl * 197 + 128 + 16 * w + l15] = accU[mt][r];
    }
  }
  __syncthreads();
  // ---- cell: liquid + LN + u + decoder + h stores (thread = node lane, col chunk c0) ----
  int c0 = __builtin_amdgcn_readfirstlane(w * 16);
  int node = base + lane;
  int ngc = node < cBN ? node : cBN - 1;
  int bb = ngc / cN, nn = ngc - bb * cN;
  float hv[16];
  {
    const float4* hp = (const float4*)(h_nm + (size_t)ngc * 64 + c0);
#pragma unroll
    for (int q = 0; q < 4; q++) {
      float4 v = hp[q];
      hv[q * 4 + 0] = v.x; hv[q * 4 + 1] = v.y; hv[q * 4 + 2] = v.z; hv[q * 4 + 3] = v.w;
    }
  }
  float acc[16];
  float pm = 0.f;
#pragma unroll
  for (int c = 0; c < 16; c++) {
    float at = tgu[lane * 197 + c0 + c] + b_tau[c0 + c];
    float ag = tgu[lane * 197 + 64 + c0 + c] + b_g[c0 + c];
    float tau = 1.f + 9.f / (1.f + __expf(-at));
    float g = tanhf(ag);
    float v = hv[c] + 0.25f * (g - hv[c]) / tau;
    acc[c] = v;
    pm += v;
  }
  redm[w * 64 + lane] = pm;
  __syncthreads();
  float mu = (redm[lane] + redm[64 + lane] + redm[128 + lane] + redm[192 + lane]) * (1.f / 64.f);
  float pv = 0.f;
#pragma unroll
  for (int c = 0; c < 16; c++) {
    float d = acc[c] - mu;
    pv += d * d;
  }
  redv[w * 64 + lane] = pv;
  __syncthreads();
  float var = (redv[lane] + redv[64 + lane] + redv[128 + lane] + redv[192 + lane]) * (1.f / 64.f);
  float rstd = rsqrtf(var + 1e-5f);
#pragma unroll
  for (int c = 0; c < 16; c++) {
    acc[c] = (acc[c] - mu) * rstd * gamma[c0 + c] + beta[c0 + c] +
             tgu[lane * 197 + 128 + c0 + c] + b_enc[c0 + c];
  }
  if (node < cBN) {
    float4* hp = (float4*)(h_nm + (size_t)ngc * 64 + c0);
#pragma unroll
    for (int q = 0; q < 4; q++) {
      float4 v;
      v.x = acc[q * 4 + 0]; v.y = acc[q * 4 + 1]; v.z = acc[q * 4 + 2]; v.w = acc[q * 4 + 3];
      hp[q] = v;
    }
    unsigned* bp = (unsigned*)(h_bf + (size_t)ngc * 64 + c0);
#pragma unroll
    for (int q = 0; q < 8; q++) {
      unsigned lo = f2b(acc[q * 2 + 0]);
      unsigned hi = f2b(acc[q * 2 + 1]);
      bp[q] = (hi << 16) | lo;
    }
  }
  // decoder fastkan + softplus
  float dc0 = cdec[0], dc7 = cdec[7];
  float inv_d = 7.f / (dc7 - dc0);
  float p0 = 0.f, p1 = 0.f, p2 = 0.f;
#pragma unroll
  for (int c = 0; c < 16; c++) {
#pragma unroll
    for (int j = 0; j < 8; j++) {
      float dd = (acc[c] - cdec[j]) * inv_d;
      float ph = __expf(-dd * dd);
      int bx = ((c0 + c) * 8 + j) * 3;
      p0 += ph * W_dec[bx];
      p1 += ph * W_dec[bx + 1];
      p2 += ph * W_dec[bx + 2];
    }
  }
  redp[(w * 3 + 0) * 64 + lane] = p0;
  redp[(w * 3 + 1) * 64 + lane] = p1;
  redp[(w * 3 + 2) * 64 + lane] = p2;
  __syncthreads();
  if (w == 0 && node < cBN) {
    float v0 = redp[0 * 64 + lane] + redp[3 * 64 + lane] + redp[6 * 64 + lane] +
               redp[9 * 64 + lane] + b_dec[0];
    float v1 = redp[1 * 64 + lane] + redp[4 * 64 + lane] + redp[7 * 64 + lane] +
               redp[10 * 64 + lane] + b_dec[1];
    float v2 = redp[2 * 64 + lane] + redp[5 * 64 + lane] + redp[8 * 64 + lane] +
               redp[11 * 64 + lane] + b_dec[2];
    size_t ob = (((size_t)bb * cT + t) * cN + nn) * 3;
    out[ob] = fmaxf(v0, 0.f) + log1pf(expf(-fabsf(v0)));
    out[ob + 1] = fmaxf(v1, 0.f) + log1pf(expf(-fabsf(v1)));
    out[ob + 2] = fmaxf(v2, 0.f) + log1pf(expf(-fabsf(v2)));
  }
}

extern "C" void kernel_launch(void* const* d_in, const int* in_sizes, int n_in, void* d_out,
                              int out_size, void* d_ws, size_t ws_size, hipStream_t stream) {
  fp x = (fp)d_in[0];
  fp edge_attr = (fp)d_in[1];
  fp c_enc = (fp)d_in[2];
  fp W_enc = (fp)d_in[3];
  fp b_enc = (fp)d_in[4];
  fp W_hop = (fp)d_in[5];
  fp a_src = (fp)d_in[6];
  fp a_dst = (fp)d_in[7];
  fp w_lt1 = (fp)d_in[8];
  fp b_lt1 = (fp)d_in[9];
  fp w_lt2 = (fp)d_in[10];
  fp b_lt2 = (fp)d_in[11];
  fp W_lt = (fp)d_in[12];
  fp W_tau = (fp)d_in[13];
  fp b_tau = (fp)d_in[14];
  fp W_g = (fp)d_in[15];
  fp b_g = (fp)d_in[16];
  fp gamma = (fp)d_in[17];
  fp beta = (fp)d_in[18];
  fp c_dec = (fp)d_in[19];
  fp W_dec = (fp)d_in[20];
  fp b_dec = (fp)d_in[21];
  fp h0 = (fp)d_in[22];
  const int* eidx = (const int*)d_in[23];
  const int* esrc_in = eidx;
  const int* edst_in = eidx + cE;

  float* fws = (float*)d_ws;
  float* h_nm = fws;     fws += cBNH;  // node-major fp32 h
  float* cur_nm = fws;   fws += cBNH;
  float* khsum_nm = fws; fws += cBNH;
  float* agg_nm = fws;   fws += cBNH;
  float* ssrc = fws;     fws += cBN;
  float* sdst = fws;     fws += cBN;
  float* gcsr = fws;     fws += cE;
  bh* h_bf = (bh*)fws;   fws += cBNH / 2;
  bh* hw_bf = (bh*)fws;  fws += cBNH / 2;
  unsigned short* Wtg = (unsigned short*)fws;   fws += (128 * 160) / 2;
  unsigned short* Wenc = (unsigned short*)fws;  fws += (64 * 128) / 2;
  unsigned short* Wlt = (unsigned short*)fws;   fws += (64 * 64) / 2;
  int* iws = (int*)fws;
  int* esrc = iws;       iws += cE;
  int* row_ptr = iws;    iws += cN + 1;
  int* cursor = iws;     iws += cN;
  int* counts = iws;     iws += cN;

  k_zero_i32<<<(cN + 255) / 256, 256, 0, stream>>>(counts, cN);
  k_count<<<(cE + 255) / 256, 256, 0, stream>>>(edst_in, counts);
  k_scan<<<1, 1024, 0, stream>>>(counts, row_ptr, cursor);
  k_scatter<<<(cE + 255) / 256, 256, 0, stream>>>(esrc_in, edst_in, edge_attr, w_lt1, b_lt1,
                                                  w_lt2, b_lt2, cursor, esrc, gcsr);
  k_init<<<(cBNH + 255) / 256, 256, 0, stream>>>(h_nm, h_bf, h0);
  k_wpack<<<(128 * 160 + 64 * 128 + 64 * 64 + 255) / 256, 256, 0, stream>>>(
      W_tau, W_g, W_enc, W_lt, Wtg, Wenc, Wlt);

  for (int t = 0; t < cT; t++) {
    for (int k = 0; k < cK; k++) {
      k_hop_mat_t<<<NBLK, 256, 0, stream>>>(k == 0 ? h_nm : cur_nm, W_hop + (size_t)k * cH * cH,
                                            a_src + k * cH, a_dst + k * cH, hw_bf, ssrc, sdst);
      k_hop_agg<<<cBN / 4, 256, 0, stream>>>(hw_bf, ssrc, sdst, row_ptr, esrc, gcsr, h_bf,
                                             cur_nm, khsum_nm, agg_nm, k);
    }
    k_mega<<<NBLK, 256, 0, stream>>>(x, t, h_nm, h_bf, khsum_nm, agg_nm, row_ptr, Wtg, Wenc,
                                     Wlt, b_tau, b_g, b_enc, gamma, beta, c_enc, c_dec, W_dec,
                                     b_dec, (float*)d_out);
  }
}

// Round 11
// 621.993 us; speedup vs baseline: 1.8606x; 1.1909x over previous
//
#include <hip/hip_runtime.h>
#include <hip/hip_bf16.h>
#include <math.h>

// SeaLiceGLKAN — fp32 in/out. Dense chain = MFMA mega-kernel; hop matvec = MFMA
// (bf16 in/out); hop aggregate = two-phase softmax w/o max-shift, bf16 gathers.

constexpr int cB = 2, cT = 4, cN = 10000, cF = 16, cH = 64, cE = 160000, cNB = 8, cK = 3;
constexpr int cBN = cB * cN;    // 20000
constexpr int cBNH = cBN * cH;  // 1,280,000
constexpr int NBLK = (cBN + 63) / 64;  // 313 nodegroups of 64

typedef const float* fp;
typedef __hip_bfloat16 bh;
typedef short short8 __attribute__((ext_vector_type(8)));
typedef float f32x4 __attribute__((ext_vector_type(4)));

__device__ __forceinline__ float wsum(float v) {
#pragma unroll
  for (int o = 1; o < 64; o <<= 1) v += __shfl_xor(v, o, 64);
  return v;
}
__device__ __forceinline__ unsigned short f2b(float f) {  // fp32 -> bf16 bits (RNE)
  unsigned u = __float_as_uint(f);
  u += 0x7FFFu + ((u >> 16) & 1u);
  return (unsigned short)(u >> 16);
}
__device__ __forceinline__ float b2f(unsigned short b) {
  return __uint_as_float(((unsigned)b) << 16);
}

// ---------------- CSR build ----------------
__global__ void k_zero_i32(int* p, int n) {
  int i = blockIdx.x * 256 + threadIdx.x;
  if (i < n) p[i] = 0;
}

__global__ void k_count(const int* dst, int* counts) {
  int e = blockIdx.x * 256 + threadIdx.x;
  if (e < cE) atomicAdd(&counts[dst[e]], 1);
}

__global__ void k_scan(const int* counts, int* row_ptr, int* cursor) {
  __shared__ int part[1024];
  int t = threadIdx.x;
  const int CH = (cN + 1023) / 1024;  // 10
  int s = 0;
  for (int i = 0; i < CH; i++) {
    int idx = t * CH + i;
    if (idx < cN) s += counts[idx];
  }
  part[t] = s;
  __syncthreads();
  for (int off = 1; off < 1024; off <<= 1) {
    int v = (t >= off) ? part[t - off] : 0;
    __syncthreads();
    part[t] += v;
    __syncthreads();
  }
  int excl = (t == 0) ? 0 : part[t - 1];
  for (int i = 0; i < CH; i++) {
    int idx = t * CH + i;
    if (idx < cN) {
      row_ptr[idx] = excl;
      cursor[idx] = excl;
      excl += counts[idx];
    }
  }
  if (t == 1023) row_ptr[cN] = part[1023];
}

__global__ void k_scatter(const int* src, const int* dst, fp ea, fp w1, fp b1, fp w2, fp b2,
                          int* cursor, int* esrc, float* gcsr) {
  int e = blockIdx.x * 256 + threadIdx.x;
  if (e >= cE) return;
  float a0 = ea[e * 4 + 0], a1 = ea[e * 4 + 1], a2 = ea[e * 4 + 2], a3 = ea[e * 4 + 3];
  float acc = b2[0];
#pragma unroll
  for (int j = 0; j < 16; j++) {
    float tv = b1[j] + a0 * w1[j] + a1 * w1[16 + j] + a2 * w1[32 + j] + a3 * w1[48 + j];
    acc += tanhf(tv) * w2[j];
  }
  float g = 1.f / (1.f + expf(-acc));
  int p = atomicAdd(&cursor[dst[e]], 1);
  esrc[p] = src[e];
  gcsr[p] = g;
}

__global__ void k_init(float* h, bh* h_bf, fp h0) {
  int i = blockIdx.x * 256 + threadIdx.x;
  if (i < cBNH) {
    float v = h0[i & 63];
    h[i] = v;
    h_bf[i] = __float2bfloat16(v);
  }
}

// ---------------- weight prepack (col-major bf16, K padded) ----------------
__global__ void k_wpack(fp W_tau, fp W_g, fp W_enc, fp W_lt, fp W_hop, unsigned short* Wtg,
                        unsigned short* Wenc, unsigned short* Wlt, unsigned short* Whop) {
  int i = blockIdx.x * 256 + threadIdx.x;
  if (i < 128 * 160) {
    int col = i / 160, k = i - col * 160;
    float v = 0.f;
    if (k < 133) v = (col < 64) ? W_tau[k * 64 + col] : W_g[k * 64 + (col - 64)];
    Wtg[i] = f2b(v);
  } else if (i < 128 * 160 + 64 * 128) {
    int i2 = i - 128 * 160;
    int col = i2 / 128, k = i2 - col * 128;
    Wenc[i2] = f2b(W_enc[k * 64 + col]);
  } else if (i < 128 * 160 + 64 * 128 + 64 * 64) {
    int i3 = i - 128 * 160 - 64 * 128;
    int col = i3 / 64, k = i3 - col * 64;
    Wlt[i3] = f2b(W_lt[k * 64 + col]);
  } else if (i < 128 * 160 + 64 * 128 + 64 * 64 + 3 * 64 * 64) {
    int i4 = i - 128 * 160 - 64 * 128 - 64 * 64;
    int hop = i4 / 4096, rem = i4 - hop * 4096;
    int col = rem / 64, k = rem - col * 64;
    Whop[i4] = f2b(W_hop[hop * 4096 + k * 64 + col]);
  }
}

// ---------------- hop matvec: MFMA, bf16 in/out ----------------
__global__ __launch_bounds__(256) void k_hop_mat_m(const bh* vin_bf, const unsigned short* Wh,
                                                   fp avs, fp avd, bh* hw_bf, float* ssrc,
                                                   float* sdst) {
  __shared__ unsigned short tin[64 * 72];
  __shared__ unsigned short thw[64 * 72];
  __shared__ float red1[4][64], red2[4][64];
  int tid = threadIdx.x, w = tid >> 6, lane = tid & 63;
  int quad = lane >> 4, l15 = lane & 15;
  int base = blockIdx.x * 64;
  // stage A (bf16 node-major, coalesced 32 B/thread)
  {
    int tn = tid >> 2, cs = (tid & 3) * 16;
    int gn = base + tn;
    if (gn >= cBN) gn = cBN - 1;
    const short8* src = (const short8*)((const unsigned short*)vin_bf + (size_t)gn * 64 + cs);
    *(short8*)(tin + tn * 72 + cs) = src[0];
    *(short8*)(tin + tn * 72 + cs + 8) = src[1];
  }
  __syncthreads();
  f32x4 acc[4];
#pragma unroll
  for (int mt = 0; mt < 4; mt++) acc[mt] = (f32x4){0.f, 0.f, 0.f, 0.f};
#pragma unroll
  for (int ks = 0; ks < 2; ks++) {
    short8 bfr = *(const short8*)(Wh + (16 * w + l15) * 64 + ks * 32 + quad * 8);
#pragma unroll
    for (int mt = 0; mt < 4; mt++) {
      short8 afr = *(const short8*)(tin + (mt * 16 + l15) * 72 + ks * 32 + quad * 8);
      acc[mt] = __builtin_amdgcn_mfma_f32_16x16x32_bf16(afr, bfr, acc[mt], 0, 0, 0);
    }
  }
  // write hw tile to LDS bf16
  int col = 16 * w + l15;
#pragma unroll
  for (int mt = 0; mt < 4; mt++) {
#pragma unroll
    for (int r = 0; r < 4; r++) {
      thw[(mt * 16 + quad * 4 + r) * 72 + col] = f2b(acc[mt][r]);
    }
  }
  __syncthreads();
  // attention partials: wave w sums cols [16w,16w+16) for node=lane
  {
    float r1 = 0.f, r2 = 0.f;
#pragma unroll
    for (int c = 0; c < 16; c++) {
      float v = b2f(thw[lane * 72 + 16 * w + c]);
      r1 += v * avs[16 * w + c];
      r2 += v * avd[16 * w + c];
    }
    red1[w][lane] = r1;
    red2[w][lane] = r2;
  }
  __syncthreads();
  if (w == 0 && base + lane < cBN) {
    ssrc[base + lane] = red1[0][lane] + red1[1][lane] + red1[2][lane] + red1[3][lane];
    sdst[base + lane] = red2[0][lane] + red2[1][lane] + red2[2][lane] + red2[3][lane];
  }
  // coalesced hw_bf store: 32 B/thread
  {
    int tn = tid >> 2, cs = (tid & 3) * 16;
    int gn = base + tn;
    if (gn < cBN) {
      short8* dst = (short8*)((unsigned short*)hw_bf + (size_t)gn * 64 + cs);
      dst[0] = *(const short8*)(thw + tn * 72 + cs);
      dst[1] = *(const short8*)(thw + tn * 72 + cs + 8);
    }
  }
}

// ---------------- hop aggregate: softmax w/o max-shift, readlane broadcasts -----------
__global__ __launch_bounds__(256) void k_hop_agg(const bh* hw_bf, const float* ssrc,
                                                 const float* sdst, const int* row_ptr,
                                                 const int* esrc, const float* gcsr,
                                                 const bh* h_bf, bh* cur_bf, float* khsum_nm,
                                                 float* agg_nm, int hop) {
  int w = threadIdx.x >> 6, lane = threadIdx.x & 63;
  int node = blockIdx.x * 4 + w;
  int b = node / cN, n = node - b * cN;
  int r0 = row_ptr[n], r1 = row_ptr[n + 1];
  const float* sb = ssrc + (size_t)b * cN;
  float sd = sdst[node];
  float den = 0.f, num = 0.f, lacc = 0.f;
  const bh* hwb = hw_bf + (size_t)b * cN * cH;
  const bh* hb = h_bf + (size_t)b * cN * cH;
  for (int e0 = r0; e0 < r1; e0 += 64) {
    int e = e0 + lane;
    bool vld = e < r1;
    int s = vld ? esrc[e] : 0;
    float g = (hop == 0 && vld) ? gcsr[e] : 0.f;
    float a = 0.f;
    if (vld) {
      float ev = sb[s] + sd;
      ev = ev > 0.f ? ev : 0.2f * ev;
      a = __expf(ev);  // |ev| small; softmax shift-invariant
    }
    den += a;
    int cnt = min(64, r1 - e0);
    for (int j = 0; j < cnt; j++) {
      int sj = __builtin_amdgcn_readlane(s, j);
      float aj = __uint_as_float(__builtin_amdgcn_readlane(__float_as_uint(a), j));
      num += aj * __bfloat162float(hwb[(size_t)sj * cH + lane]);
      if (hop == 0) {
        float gj = __uint_as_float(__builtin_amdgcn_readlane(__float_as_uint(g), j));
        lacc += gj * __bfloat162float(hb[(size_t)sj * cH + lane]);
      }
    }
  }
  den = wsum(den);
  float cv = num / (den + 1e-16f);
  size_t ni = (size_t)node * 64 + lane;
  if (hop < 2) cur_bf[ni] = __float2bfloat16(cv);
  if (hop == 0) {
    khsum_nm[ni] = cv;
    agg_nm[ni] = lacc;
  } else {
    khsum_nm[ni] += cv;
  }
}

// ---------------- MFMA mega-kernel: p-GEMM + tau/g GEMM + u GEMM + cell ----------------
__global__ __launch_bounds__(256) void k_mega(fp x, int t, float* h_nm, bh* h_bf,
                                              const float* khsum_nm, const float* agg_nm,
                                              const int* row_ptr, const unsigned short* Wtg,
                                              const unsigned short* Wenc,
                                              const unsigned short* Wlt, fp b_tau, fp b_g,
                                              fp b_enc, fp gamma, fp beta, fp c_enc, fp cdec,
                                              fp W_dec, fp b_dec, float* out) {
  __shared__ __align__(16) char lds[59904];
  unsigned short* tz = (unsigned short*)lds;
  unsigned short* tagg = (unsigned short*)(lds + 21504);
  unsigned short* tphi = (unsigned short*)(lds + 30720);
  float* tgu = (float*)lds;
  float* sx = (float*)(lds + 50432);
  float* redm = (float*)(lds + 54784);          // [4][64]
  float* redv = redm + 256;                     // [4][64]
  float* redp = redv + 256;                     // [4][3][64]
  int tid = threadIdx.x;
  int w = tid >> 6, lane = tid & 63;
  int quad = lane >> 4, l15 = lane & 15;
  int base = blockIdx.x * 64;
  {
    int tn = tid >> 2, f4 = (tid & 3) * 4;
    int gn = base + tn;
    if (gn >= cBN) gn = cBN - 1;
    int gb = gn / cN, gnn = gn - gb * cN;
    float4 xv = *(const float4*)(x + (((size_t)gb * cT + t) * cN + gnn) * cF + f4);
    sx[tn * 17 + f4 + 0] = xv.x;
    sx[tn * 17 + f4 + 1] = xv.y;
    sx[tn * 17 + f4 + 2] = xv.z;
    sx[tn * 17 + f4 + 3] = xv.w;
    int f0 = (tid & 3) * 16;
    const float4* hsrc = (const float4*)(h_nm + (size_t)gn * 64 + f0);
    const float4* asrc = (const float4*)(agg_nm + (size_t)gn * 64 + f0);
#pragma unroll
    for (int q = 0; q < 4; q++) {
      float4 hv = hsrc[q];
      float4 av = asrc[q];
      int k = f0 + q * 4;
      tz[tn * 168 + k + 0] = f2b(hv.x); tz[tn * 168 + k + 1] = f2b(hv.y);
      tz[tn * 168 + k + 2] = f2b(hv.z); tz[tn * 168 + k + 3] = f2b(hv.w);
      tagg[tn * 72 + k + 0] = f2b(av.x); tagg[tn * 72 + k + 1] = f2b(av.y);
      tagg[tn * 72 + k + 2] = f2b(av.z); tagg[tn * 72 + k + 3] = f2b(av.w);
    }
  }
  for (int i = tid; i < 64 * 27; i += 256) {
    int nn2 = i / 27, kk = 133 + (i - nn2 * 27);
    tz[nn2 * 168 + kk] = 0;
  }
  __syncthreads();
  for (int i = tid; i < 320; i += 256) {
    int j = i >> 6, n2 = i & 63;
    tz[n2 * 168 + 64 + j] = f2b(sx[n2 * 17 + 8 + j]);
  }
  {
    float ec0 = c_enc[0], ec7 = c_enc[7];
    float inv_e = 7.f / (ec7 - ec0);
    for (int i = tid; i < 64 * 128; i += 256) {
      int n2 = i >> 7, j = i & 127;
      int f = j >> 3, cb = j & 7;
      float d = (sx[n2 * 17 + f] - c_enc[cb]) * inv_e;
      tphi[n2 * 136 + j] = f2b(__expf(-d * d));
    }
  }
  __syncthreads();
  f32x4 accU[4];
#pragma unroll
  for (int mt = 0; mt < 4; mt++) accU[mt] = (f32x4){0.f, 0.f, 0.f, 0.f};
#pragma unroll
  for (int ks = 0; ks < 4; ks++) {
    short8 bfr = *(const short8*)(Wenc + (16 * w + l15) * 128 + ks * 32 + quad * 8);
#pragma unroll
    for (int mt = 0; mt < 4; mt++) {
      short8 afr = *(const short8*)(tphi + (mt * 16 + l15) * 136 + ks * 32 + quad * 8);
      accU[mt] = __builtin_amdgcn_mfma_f32_16x16x32_bf16(afr, bfr, accU[mt], 0, 0, 0);
    }
  }
  {
    f32x4 accP[4];
#pragma unroll
    for (int mt = 0; mt < 4; mt++) accP[mt] = (f32x4){0.f, 0.f, 0.f, 0.f};
#pragma unroll
    for (int ks = 0; ks < 2; ks++) {
      short8 bfr = *(const short8*)(Wlt + (16 * w + l15) * 64 + ks * 32 + quad * 8);
#pragma unroll
      for (int mt = 0; mt < 4; mt++) {
        short8 afr = *(const short8*)(tagg + (mt * 16 + l15) * 72 + ks * 32 + quad * 8);
        accP[mt] = __builtin_amdgcn_mfma_f32_16x16x32_bf16(afr, bfr, accP[mt], 0, 0, 0);
      }
    }
    int colP = 16 * w + l15;
#pragma unroll
    for (int mt = 0; mt < 4; mt++) {
#pragma unroll
      for (int r = 0; r < 4; r++) {
        int nl = mt * 16 + quad * 4 + r;
        int ng = base + nl;
        int ngc = ng < cBN ? ng : cBN - 1;
        int bB = ngc / cN, nn = ngc - bB * cN;
        float deg = (float)(row_ptr[nn + 1] - row_ptr[nn]);
        float pval = khsum_nm[(size_t)ngc * 64 + colP] * (1.f / 3.f) +
                     accP[mt][r] / (deg + 1.f);
        tz[nl * 168 + 69 + colP] = f2b(pval);
      }
    }
  }
  __syncthreads();
  f32x4 accT[8];
#pragma unroll
  for (int i = 0; i < 8; i++) accT[i] = (f32x4){0.f, 0.f, 0.f, 0.f};
#pragma unroll
  for (int ks = 0; ks < 5; ks++) {
    short8 b0 = *(const short8*)(Wtg + (32 * w + l15) * 160 + ks * 32 + quad * 8);
    short8 b1 = *(const short8*)(Wtg + (32 * w + 16 + l15) * 160 + ks * 32 + quad * 8);
#pragma unroll
    for (int mt = 0; mt < 4; mt++) {
      short8 afr = *(const short8*)(tz + (mt * 16 + l15) * 168 + ks * 32 + quad * 8);
      accT[mt * 2 + 0] = __builtin_amdgcn_mfma_f32_16x16x32_bf16(afr, b0, accT[mt * 2 + 0], 0, 0, 0);
      accT[mt * 2 + 1] = __builtin_amdgcn_mfma_f32_16x16x32_bf16(afr, b1, accT[mt * 2 + 1], 0, 0, 0);
    }
  }
  __syncthreads();
#pragma unroll
  for (int mt = 0; mt < 4; mt++) {
#pragma unroll
    for (int ntl = 0; ntl < 2; ntl++) {
#pragma unroll
      for (int r = 0; r < 4; r++) {
        int nl = mt * 16 + quad * 4 + r;
        int col = 32 * w + ntl * 16 + l15;
        tgu[nl * 197 + col] = accT[mt * 2 + ntl][r];
      }
    }
#pragma unroll
    for (int r = 0; r < 4; r++) {
      int nl = mt * 16 + quad * 4 + r;
      tgu[nl * 197 + 128 + 16 * w + l15] = accU[mt][r];
    }
  }
  __syncthreads();
  int c0 = __builtin_amdgcn_readfirstlane(w * 16);
  int node = base + lane;
  int ngc = node < cBN ? node : cBN - 1;
  int bb = ngc / cN, nn = ngc - bb * cN;
  float hv[16];
  {
    const float4* hp = (const float4*)(h_nm + (size_t)ngc * 64 + c0);
#pragma unroll
    for (int q = 0; q < 4; q++) {
      float4 v = hp[q];
      hv[q * 4 + 0] = v.x; hv[q * 4 + 1] = v.y; hv[q * 4 + 2] = v.z; hv[q * 4 + 3] = v.w;
    }
  }
  float acc[16];
  float pm = 0.f;
#pragma unroll
  for (int c = 0; c < 16; c++) {
    float at = tgu[lane * 197 + c0 + c] + b_tau[c0 + c];
    float ag = tgu[lane * 197 + 64 + c0 + c] + b_g[c0 + c];
    float tau = 1.f + 9.f / (1.f + __expf(-at));
    float g = tanhf(ag);
    float v = hv[c] + 0.25f * (g - hv[c]) / tau;
    acc[c] = v;
    pm += v;
  }
  redm[w * 64 + lane] = pm;
  __syncthreads();
  float mu = (redm[lane] + redm[64 + lane] + redm[128 + lane] + redm[192 + lane]) * (1.f / 64.f);
  float pv = 0.f;
#pragma unroll
  for (int c = 0; c < 16; c++) {
    float d = acc[c] - mu;
    pv += d * d;
  }
  redv[w * 64 + lane] = pv;
  __syncthreads();
  float var = (redv[lane] + redv[64 + lane] + redv[128 + lane] + redv[192 + lane]) * (1.f / 64.f);
  float rstd = rsqrtf(var + 1e-5f);
#pragma unroll
  for (int c = 0; c < 16; c++) {
    acc[c] = (acc[c] - mu) * rstd * gamma[c0 + c] + beta[c0 + c] +
             tgu[lane * 197 + 128 + c0 + c] + b_enc[c0 + c];
  }
  if (node < cBN) {
    float4* hp = (float4*)(h_nm + (size_t)ngc * 64 + c0);
#pragma unroll
    for (int q = 0; q < 4; q++) {
      float4 v;
      v.x = acc[q * 4 + 0]; v.y = acc[q * 4 + 1]; v.z = acc[q * 4 + 2]; v.w = acc[q * 4 + 3];
      hp[q] = v;
    }
    unsigned* bp = (unsigned*)(h_bf + (size_t)ngc * 64 + c0);
#pragma unroll
    for (int q = 0; q < 8; q++) {
      unsigned lo = f2b(acc[q * 2 + 0]);
      unsigned hi = f2b(acc[q * 2 + 1]);
      bp[q] = (hi << 16) | lo;
    }
  }
  float dc0 = cdec[0], dc7 = cdec[7];
  float inv_d = 7.f / (dc7 - dc0);
  float p0 = 0.f, p1 = 0.f, p2 = 0.f;
#pragma unroll
  for (int c = 0; c < 16; c++) {
#pragma unroll
    for (int j = 0; j < 8; j++) {
      float dd = (acc[c] - cdec[j]) * inv_d;
      float ph = __expf(-dd * dd);
      int bx = ((c0 + c) * 8 + j) * 3;
      p0 += ph * W_dec[bx];
      p1 += ph * W_dec[bx + 1];
      p2 += ph * W_dec[bx + 2];
    }
  }
  redp[(w * 3 + 0) * 64 + lane] = p0;
  redp[(w * 3 + 1) * 64 + lane] = p1;
  redp[(w * 3 + 2) * 64 + lane] = p2;
  __syncthreads();
  if (w == 0 && node < cBN) {
    float v0 = redp[0 * 64 + lane] + redp[3 * 64 + lane] + redp[6 * 64 + lane] +
               redp[9 * 64 + lane] + b_dec[0];
    float v1 = redp[1 * 64 + lane] + redp[4 * 64 + lane] + redp[7 * 64 + lane] +
               redp[10 * 64 + lane] + b_dec[1];
    float v2 = redp[2 * 64 + lane] + redp[5 * 64 + lane] + redp[8 * 64 + lane] +
               redp[11 * 64 + lane] + b_dec[2];
    size_t ob = (((size_t)bb * cT + t) * cN + nn) * 3;
    out[ob] = fmaxf(v0, 0.f) + log1pf(expf(-fabsf(v0)));
    out[ob + 1] = fmaxf(v1, 0.f) + log1pf(expf(-fabsf(v1)));
    out[ob + 2] = fmaxf(v2, 0.f) + log1pf(expf(-fabsf(v2)));
  }
}

extern "C" void kernel_launch(void* const* d_in, const int* in_sizes, int n_in, void* d_out,
                              int out_size, void* d_ws, size_t ws_size, hipStream_t stream) {
  fp x = (fp)d_in[0];
  fp edge_attr = (fp)d_in[1];
  fp c_enc = (fp)d_in[2];
  fp W_enc = (fp)d_in[3];
  fp b_enc = (fp)d_in[4];
  fp W_hop = (fp)d_in[5];
  fp a_src = (fp)d_in[6];
  fp a_dst = (fp)d_in[7];
  fp w_lt1 = (fp)d_in[8];
  fp b_lt1 = (fp)d_in[9];
  fp w_lt2 = (fp)d_in[10];
  fp b_lt2 = (fp)d_in[11];
  fp W_lt = (fp)d_in[12];
  fp W_tau = (fp)d_in[13];
  fp b_tau = (fp)d_in[14];
  fp W_g = (fp)d_in[15];
  fp b_g = (fp)d_in[16];
  fp gamma = (fp)d_in[17];
  fp beta = (fp)d_in[18];
  fp c_dec = (fp)d_in[19];
  fp W_dec = (fp)d_in[20];
  fp b_dec = (fp)d_in[21];
  fp h0 = (fp)d_in[22];
  const int* eidx = (const int*)d_in[23];
  const int* esrc_in = eidx;
  const int* edst_in = eidx + cE;

  float* fws = (float*)d_ws;
  float* h_nm = fws;     fws += cBNH;
  float* khsum_nm = fws; fws += cBNH;
  float* agg_nm = fws;   fws += cBNH;
  float* ssrc = fws;     fws += cBN;
  float* sdst = fws;     fws += cBN;
  float* gcsr = fws;     fws += cE;
  bh* h_bf = (bh*)fws;   fws += cBNH / 2;
  bh* hw_bf = (bh*)fws;  fws += cBNH / 2;
  bh* cur_bf = (bh*)fws; fws += cBNH / 2;
  unsigned short* Wtg = (unsigned short*)fws;   fws += (128 * 160) / 2;
  unsigned short* Wenc = (unsigned short*)fws;  fws += (64 * 128) / 2;
  unsigned short* Wlt = (unsigned short*)fws;   fws += (64 * 64) / 2;
  unsigned short* Whop = (unsigned short*)fws;  fws += (3 * 64 * 64) / 2;
  int* iws = (int*)fws;
  int* esrc = iws;       iws += cE;
  int* row_ptr = iws;    iws += cN + 1;
  int* cursor = iws;     iws += cN;
  int* counts = iws;     iws += cN;

  k_zero_i32<<<(cN + 255) / 256, 256, 0, stream>>>(counts, cN);
  k_count<<<(cE + 255) / 256, 256, 0, stream>>>(edst_in, counts);
  k_scan<<<1, 1024, 0, stream>>>(counts, row_ptr, cursor);
  k_scatter<<<(cE + 255) / 256, 256, 0, stream>>>(esrc_in, edst_in, edge_attr, w_lt1, b_lt1,
                                                  w_lt2, b_lt2, cursor, esrc, gcsr);
  k_init<<<(cBNH + 255) / 256, 256, 0, stream>>>(h_nm, h_bf, h0);
  int wtot = 128 * 160 + 64 * 128 + 64 * 64 + 3 * 64 * 64;
  k_wpack<<<(wtot + 255) / 256, 256, 0, stream>>>(W_tau, W_g, W_enc, W_lt, W_hop, Wtg, Wenc,
                                                  Wlt, Whop);

  for (int t = 0; t < cT; t++) {
    for (int k = 0; k < cK; k++) {
      k_hop_mat_m<<<NBLK, 256, 0, stream>>>(k == 0 ? h_bf : cur_bf, Whop + k * 4096,
                                            a_src + k * cH, a_dst + k * cH, hw_bf, ssrc, sdst);
      k_hop_agg<<<cBN / 4, 256, 0, stream>>>(hw_bf, ssrc, sdst, row_ptr, esrc, gcsr, h_bf,
                                             cur_bf, khsum_nm, agg_nm, k);
    }
    k_mega<<<NBLK, 256, 0, stream>>>(x, t, h_nm, h_bf, khsum_nm, agg_nm, row_ptr, Wtg, Wenc,
                                     Wlt, b_tau, b_g, b_enc, gamma, beta, c_enc, c_dec, W_dec,
                                     b_dec, (float*)d_out);
  }
}